// Round 1
// baseline (202.856 us; speedup 1.0000x reference)
//
#include <hip/hip_runtime.h>
#include <stdint.h>

#define AS1 __attribute__((address_space(1)))
#define AS3 __attribute__((address_space(3)))

typedef short short8 __attribute__((ext_vector_type(8)));
typedef unsigned short ushort8 __attribute__((ext_vector_type(8)));
typedef __bf16 bf16x8 __attribute__((ext_vector_type(8)));
typedef float floatx4 __attribute__((ext_vector_type(4)));

__device__ __forceinline__ floatx4 mfma16(short8 a, short8 b, floatx4 c) {
  return __builtin_amdgcn_mfma_f32_16x16x32_bf16(
      __builtin_bit_cast(bf16x8, a), __builtin_bit_cast(bf16x8, b), c, 0, 0, 0);
}

__device__ __forceinline__ unsigned short f2bf(float f) {
  uint32_t u = __builtin_bit_cast(uint32_t, f);
  u = (u + 0x7FFFu + ((u >> 16) & 1u)) >> 16;
  return (unsigned short)u;
}

// packed f32x2 -> bf16x2, 1 VALU instr for 2 values
__device__ __forceinline__ uint32_t cvt_pk_bf16(float a, float b) {
  uint32_t d;
  asm("v_cvt_pk_bf16_f32 %0, %1, %2" : "=v"(d) : "v"(a), "v"(b));
  return d;
}

// ---------------------------------------------------------------------------
// Convert/pack: x -> bf16, Wq|Wk|Wv -> Wqkv (3072x1024 bf16), Wo -> bf16.
// ---------------------------------------------------------------------------
__global__ __launch_bounds__(256) void convert_pack(
    const float4* __restrict__ x, const float4* __restrict__ wq,
    const float4* __restrict__ wk, const float4* __restrict__ wv,
    const float4* __restrict__ wo, ushort4* __restrict__ xb,
    ushort4* __restrict__ wqkvb, ushort4* __restrict__ wob) {
  int i = blockIdx.x * 256 + threadIdx.x;
  const float4* src;
  ushort4* dst;
  if (i < (1 << 20)) {
    src = x + i;
    dst = xb + i;
  } else {
    int t = i - (1 << 20);
    int r = t >> 18;
    int j = t & ((1 << 18) - 1);
    src = (r == 0 ? wq : r == 1 ? wk : r == 2 ? wv : wo) + j;
    dst = (r < 3) ? (wqkvb + (r << 18) + j) : (wob + j);
  }
  float4 v = *src;
  ushort4 o;
  o.x = f2bf(v.x);
  o.y = f2bf(v.y);
  o.z = f2bf(v.z);
  o.w = f2bf(v.w);
  *dst = o;
}

// ---------------------------------------------------------------------------
// GEMM 128x128 tile (QKV projection): C[M][N] = A[M][K] @ B[N][K]^T.
// L3-BW fix: (a) XCD-compact supertile swizzle so all sharers of an A/B
// panel are co-resident on ONE XCD (panel re-reads become L2 hits instead of
// L3: measured 59us == 384MB panel traffic / 6.5 TB/s); (b) double-buffered
// 2-phase staging so the global_load_lds for K-step t+1 land under the MFMA
// phase of step t (one barrier per K-step).
// ---------------------------------------------------------------------------
template <typename OutT>
__global__ __launch_bounds__(256) void gemm_bt(const unsigned short* __restrict__ A,
                                               const unsigned short* __restrict__ Bm,
                                               OutT* __restrict__ C, int N, int K) {
  __shared__ unsigned short lds[2][32 * 512];  // 2 x 32 KB
  const int tid = threadIdx.x;
  const int lane = tid & 63;
  const int w = tid >> 6;
  const int wr = w >> 1, wc = w & 1;

  // Swizzle for grid (32,24)=768: hw linear id round-robins XCDs (lid%8).
  // Each XCD owns 3 supertiles of 8(M)x4(N) blocks; a supertile's 32 blocks
  // are co-resident on the XCD's 32 CUs. Bijective.
  const int lid = blockIdx.y * gridDim.x + blockIdx.x;
  const int xcd = lid & 7;
  const int wgid = xcd * 96 + (lid >> 3);  // 0..767, contiguous per XCD
  const int s = wgid >> 5, w5 = wgid & 31; // supertile 0..23, within 0..31
  const int mt = (s & 3) * 8 + (w5 & 7);   // 0..31
  const int nt = (s >> 2) * 4 + (w5 >> 3); // 0..23
  const int tm = mt * 128, tn = nt * 128;
  const int lrow = lane & 15;
  const int lk = (lane >> 4) * 8;

  floatx4 acc[4][4];
#pragma unroll
  for (int i = 0; i < 4; ++i)
#pragma unroll
    for (int j = 0; j < 4; ++j) acc[i][j] = floatx4{0.f, 0.f, 0.f, 0.f};

  auto stage = [&](int buf, int k0) {
#pragma unroll
    for (int c = w; c < 32; c += 4) {
      const unsigned short* g;
      if (c < 16) {
        int mtt = c >> 1, ks = c & 1;
        g = A + (size_t)(tm + mtt * 16 + lrow) * K + (k0 + ks * 32 + lk);
      } else {
        int cc = c - 16;
        int ntt = cc >> 1, ks = cc & 1;
        g = Bm + (size_t)(tn + ntt * 16 + lrow) * K + (k0 + ks * 32 + lk);
      }
      __builtin_amdgcn_global_load_lds((const AS1 uint32_t*)g,
                                       (AS3 uint32_t*)(&lds[buf][c * 512]), 16, 0, 0);
    }
  };

  stage(0, 0);
  __syncthreads();  // prologue loads landed (barrier drains vmcnt)

  const int T = K >> 6;  // 16
  for (int t = 0; t < T; ++t) {
    if (t + 1 < T) stage((t + 1) & 1, (t + 1) << 6);  // prefetch next K-step
    const unsigned short* L = lds[t & 1];
#pragma unroll
    for (int ks = 0; ks < 2; ++ks) {
      short8 af[4], bf[4];
#pragma unroll
      for (int i = 0; i < 4; ++i)
        af[i] = *(const short8*)&L[((wr * 4 + i) * 2 + ks) * 512 + lane * 8];
#pragma unroll
      for (int j = 0; j < 4; ++j)
        bf[j] = *(const short8*)&L[(16 + (wc * 4 + j) * 2 + ks) * 512 + lane * 8];
#pragma unroll
      for (int i = 0; i < 4; ++i)
#pragma unroll
        for (int j = 0; j < 4; ++j) acc[i][j] = mfma16(af[i], bf[j], acc[i][j]);
    }
    __syncthreads();  // readers of lds[t&1] done; stage(t+1) drained (landed)
  }

  const int r0 = (lane >> 4) * 4;
#pragma unroll
  for (int i = 0; i < 4; ++i)
#pragma unroll
    for (int j = 0; j < 4; ++j)
#pragma unroll
      for (int r = 0; r < 4; ++r) {
        int row = tm + wr * 64 + i * 16 + r0 + r;
        int col = tn + wc * 64 + j * 16 + lrow;
        float v = acc[i][j][r];
        if constexpr (sizeof(OutT) == 2)
          C[(size_t)row * N + col] = f2bf(v);
        else
          C[(size_t)row * N + col] = v;
      }
}

// ---------------------------------------------------------------------------
// GEMM 64x128 tile (output projection). Same two fixes: XCD-compact
// supertiles of 16(M)x2(N) blocks (grid (64,8)=512 -> 2 supertiles/XCD) and
// double-buffered 2-phase staging.
// ---------------------------------------------------------------------------
__global__ __launch_bounds__(256) void gemm64(const unsigned short* __restrict__ A,
                                              const unsigned short* __restrict__ Bm,
                                              float* __restrict__ C, int N, int K) {
  __shared__ unsigned short lds[2][24 * 512];  // 2 x 24 KB; A: 0-7, B: 8-23
  const int tid = threadIdx.x;
  const int lane = tid & 63;
  const int w = tid >> 6;
  const int wr = w >> 1, wc = w & 1;

  const int lid = blockIdx.y * gridDim.x + blockIdx.x;
  const int xcd = lid & 7;
  const int wgid = xcd * 64 + (lid >> 3);  // 0..511, contiguous per XCD
  const int s = wgid >> 5, w5 = wgid & 31; // supertile 0..15, within 0..31
  const int mt = (s & 3) * 16 + (w5 & 15); // 0..63
  const int nt = (s >> 2) * 2 + (w5 >> 4); // 0..7
  const int tm = mt * 64, tn = nt * 128;
  const int lrow = lane & 15;
  const int lk = (lane >> 4) * 8;

  floatx4 acc[2][4];
#pragma unroll
  for (int i = 0; i < 2; ++i)
#pragma unroll
    for (int j = 0; j < 4; ++j) acc[i][j] = floatx4{0.f, 0.f, 0.f, 0.f};

  auto stage = [&](int buf, int k0) {
#pragma unroll
    for (int c = w * 6; c < w * 6 + 6; ++c) {
      const unsigned short* g;
      if (c < 8) {
        int mtt = c >> 1, ks = c & 1;
        g = A + (size_t)(tm + mtt * 16 + lrow) * K + (k0 + ks * 32 + lk);
      } else {
        int cc = c - 8;
        int ntt = cc >> 1, ks = cc & 1;
        g = Bm + (size_t)(tn + ntt * 16 + lrow) * K + (k0 + ks * 32 + lk);
      }
      __builtin_amdgcn_global_load_lds((const AS1 uint32_t*)g,
                                       (AS3 uint32_t*)(&lds[buf][c * 512]), 16, 0, 0);
    }
  };

  stage(0, 0);
  __syncthreads();

  const int T = K >> 6;  // 16
  for (int t = 0; t < T; ++t) {
    if (t + 1 < T) stage((t + 1) & 1, (t + 1) << 6);
    const unsigned short* L = lds[t & 1];
#pragma unroll
    for (int ks = 0; ks < 2; ++ks) {
      short8 af[2], bf[4];
#pragma unroll
      for (int i = 0; i < 2; ++i)
        af[i] = *(const short8*)&L[((wr * 2 + i) * 2 + ks) * 512 + lane * 8];
#pragma unroll
      for (int j = 0; j < 4; ++j)
        bf[j] = *(const short8*)&L[(8 + (wc * 4 + j) * 2 + ks) * 512 + lane * 8];
#pragma unroll
      for (int i = 0; i < 2; ++i)
#pragma unroll
        for (int j = 0; j < 4; ++j) acc[i][j] = mfma16(af[i], bf[j], acc[i][j]);
    }
    __syncthreads();
  }

  const int r0 = (lane >> 4) * 4;
#pragma unroll
  for (int i = 0; i < 2; ++i)
#pragma unroll
    for (int j = 0; j < 4; ++j)
#pragma unroll
      for (int r = 0; r < 4; ++r) {
        int row = tm + (wr * 2 + i) * 16 + r0 + r;
        int col = tn + (wc * 4 + j) * 16 + lrow;
        C[(size_t)row * N + col] = acc[i][j][r];
      }
}

// ---------------------------------------------------------------------------
// Flash attention, S^T orientation, 128 q/WG, 128-key blocks + 16-key sink.
// XCD-aware mapping: h = 2*(i&7) + (i>>8) -> 2 heads per XCD (K+V ~2MB fits
// 4MB L2). Complementary qb pairing balances the 2 co-resident WGs per CU.
// Software pipeline: Klds double-buffered (global_load_lds), V prefetched to
// registers; prefetches for block n+1 issue during compute of block n so the
// barrier vmcnt drain finds them landed.
// ---------------------------------------------------------------------------
__global__ __launch_bounds__(256) void attn_kernel(const unsigned short* __restrict__ qkv,
                                                   unsigned short* __restrict__ aout) {
  __shared__ unsigned short Klds[2][16 * 512];  // 2 x 16KB A-frag chunks
  __shared__ unsigned short VT[64 * 136];       // V^T [d][key], stride 136
  __shared__ unsigned short PT[4][16 * 136];    // per-wave P^T [q][key]

  const int tid = threadIdx.x;
  const int lane = tid & 63;
  const int w = tid >> 6;
  const int lrow = lane & 15;
  const int lkg = lane >> 4;

  const int i = blockIdx.x;
  const int half = i >> 8;
  const int j = (i >> 3) & 31;
  const int h = 2 * (i & 7) + half;
  const int qb = half ? (31 - j) : j;
  const int q0 = qb * 128;

  short8 qf[2][2];
#pragma unroll
  for (int qt = 0; qt < 2; ++qt)
#pragma unroll
    for (int ks = 0; ks < 2; ++ks)
      qf[qt][ks] = *(const short8*)&qkv[(size_t)(q0 + qt * 64 + w * 16 + lrow) * 3072 +
                                        h * 64 + ks * 32 + lkg * 8];

  float m_i[2], l_i[2];
  floatx4 o[4][2];
#pragma unroll
  for (int qt = 0; qt < 2; ++qt) {
    m_i[qt] = -1e30f;
    l_i[qt] = 0.f;
#pragma unroll
    for (int nt = 0; nt < 4; ++nt) o[nt][qt] = floatx4{0.f, 0.f, 0.f, 0.f};
  }

  const float scale2 = 0.125f * 1.44269504088896f;  // 1/sqrt(64) * log2(e)

  // ---- prologue: stage sink K/V; prefetch window block 0 ----
  if (w < 2) {  // sink K chunks 0,1 into Klds[0]
    const unsigned short* g = &qkv[(size_t)lrow * 3072 + 1024 + h * 64 + w * 32 + lkg * 8];
    __builtin_amdgcn_global_load_lds((const AS1 uint32_t*)g,
                                     (AS3 uint32_t*)(&Klds[0][w * 512]), 16, 0, 0);
  }
  {  // sink V^T keys 0..31 (PV spans 0..31; P=0 for 16..31)
    if (lane < 16) {
      const unsigned short* g0 = &qkv[(size_t)(2 * lane) * 3072 + 2048 + h * 64 + w * 16];
      ushort8 a0 = *(const ushort8*)g0;
      ushort8 a1 = *(const ushort8*)(g0 + 8);
      ushort8 b0 = *(const ushort8*)(g0 + 3072);
      ushort8 b1 = *(const ushort8*)(g0 + 3080);
      uint32_t* vt = (uint32_t*)VT;
#pragma unroll
      for (int dd = 0; dd < 8; ++dd) {
        vt[(w * 16 + dd) * 68 + lane] = (uint32_t)a0[dd] | ((uint32_t)b0[dd] << 16);
        vt[(w * 16 + 8 + dd) * 68 + lane] = (uint32_t)a1[dd] | ((uint32_t)b1[dd] << 16);
      }
    }
  }
  const int kb0 = (q0 - 511 < 16) ? 16 : (q0 - 511);
  // prefetch window block 0: K -> Klds[1], V -> registers
#pragma unroll
  for (int c = 0; c < 4; ++c) {
    int ch = w * 4 + c;
    int kt = ch >> 1, ks = ch & 1;
    const unsigned short* g =
        &qkv[(size_t)(kb0 + kt * 16 + lrow) * 3072 + 1024 + h * 64 + ks * 32 + lkg * 8];
    __builtin_amdgcn_global_load_lds((const AS1 uint32_t*)g,
                                     (AS3 uint32_t*)(&Klds[1][ch * 512]), 16, 0, 0);
  }
  ushort8 va0, va1, vb0, vb1;
  {
    const unsigned short* g0 = &qkv[(size_t)(kb0 + 2 * lane) * 3072 + 2048 + h * 64 + w * 16];
    va0 = *(const ushort8*)g0;
    va1 = *(const ushort8*)(g0 + 8);
    vb0 = *(const ushort8*)(g0 + 3072);
    vb1 = *(const ushort8*)(g0 + 3080);
  }
  __syncthreads();

  // ---- sink compute (keys 0..15; PV over 0..31 with P=0 padding) ----
#pragma unroll
  for (int qt = 0; qt < 2; ++qt) {
    const int qq = q0 + qt * 64 + w * 16 + lrow;
    floatx4 s0 = floatx4{0.f, 0.f, 0.f, 0.f};
#pragma unroll
    for (int ks = 0; ks < 2; ++ks) {
      short8 kf = *(const short8*)&Klds[0][ks * 512 + lane * 8];
      s0 = mfma16(kf, qf[qt][ks], s0);
    }
    float mx = -1e30f;
    float sv[4];
#pragma unroll
    for (int r = 0; r < 4; ++r) {
      int key = lkg * 4 + r;
      bool vis = (key <= qq) && ((key < 4) || (key >= qq - 511));
      sv[r] = vis ? s0[r] * scale2 : -1e30f;
      mx = fmaxf(mx, sv[r]);
    }
    mx = fmaxf(mx, __shfl_xor(mx, 16));
    mx = fmaxf(mx, __shfl_xor(mx, 32));
    m_i[qt] = mx;  // key 0 always visible -> finite
    float p0 = exp2f(sv[0] - mx), p1 = exp2f(sv[1] - mx);
    float p2 = exp2f(sv[2] - mx), p3 = exp2f(sv[3] - mx);
    float ps = (p0 + p1) + (p2 + p3);
    *(uint2*)&PT[w][lrow * 136 + lkg * 4] = uint2{cvt_pk_bf16(p0, p1), cvt_pk_bf16(p2, p3)};
    *(uint2*)&PT[w][lrow * 136 + 16 + lkg * 4] = uint2{0u, 0u};  // keys 16..31 = 0
    ps += __shfl_xor(ps, 16);
    ps += __shfl_xor(ps, 32);
    l_i[qt] = ps;
    short8 pf = *(const short8*)&PT[w][lrow * 136 + lkg * 8];
#pragma unroll
    for (int nt = 0; nt < 4; ++nt) {
      short8 vf = *(const short8*)&VT[(nt * 16 + lrow) * 136 + lkg * 8];
      o[nt][qt] = mfma16(vf, pf, o[nt][qt]);
    }
  }

  // ---- window blocks of 128 keys (pipelined) ----
  int nbuf = 1;
  for (int kb = kb0; kb < q0 + 128; kb += 128) {
    const bool hasnext = (kb + 128 < q0 + 128);
    __syncthreads();  // prev readers of VT done; this block's K/V prefetch drained (landed)
    {  // write V^T for this block from prefetched registers
      uint32_t* vt = (uint32_t*)VT;
#pragma unroll
      for (int dd = 0; dd < 8; ++dd) {
        vt[(w * 16 + dd) * 68 + lane] = (uint32_t)va0[dd] | ((uint32_t)vb0[dd] << 16);
        vt[(w * 16 + 8 + dd) * 68 + lane] = (uint32_t)va1[dd] | ((uint32_t)vb1[dd] << 16);
      }
    }
    __syncthreads();  // VT visible

    // issue prefetches for block n+1 (after the barrier so the drain above
    // never waits on them; they land during this block's compute)
    if (hasnext) {
      const int kn = kb + 128;
#pragma unroll
      for (int c = 0; c < 4; ++c) {
        int ch = w * 4 + c;
        int kt = ch >> 1, ks = ch & 1;
        const unsigned short* g =
            &qkv[(size_t)(kn + kt * 16 + lrow) * 3072 + 1024 + h * 64 + ks * 32 + lkg * 8];
        __builtin_amdgcn_global_load_lds((const AS1 uint32_t*)g,
                                         (AS3 uint32_t*)(&Klds[1 - nbuf][ch * 512]), 16, 0, 0);
      }
      const unsigned short* g0 = &qkv[(size_t)(kn + 2 * lane) * 3072 + 2048 + h * 64 + w * 16];
      va0 = *(const ushort8*)g0;
      va1 = *(const ushort8*)(g0 + 8);
      vb0 = *(const ushort8*)(g0 + 3072);
      vb1 = *(const ushort8*)(g0 + 3080);
    }

#pragma unroll
    for (int qt = 0; qt < 2; ++qt) {
      const int qaT = q0 + qt * 64 + w * 16;  // wave-uniform
      const int qq = qaT + lrow;
      floatx4 s[8];
#pragma unroll
      for (int ct = 0; ct < 8; ++ct) {
        s[ct] = floatx4{0.f, 0.f, 0.f, 0.f};
#pragma unroll
        for (int ks = 0; ks < 2; ++ks) {
          short8 kf = *(const short8*)&Klds[nbuf][(ct * 2 + ks) * 512 + lane * 8];
          s[ct] = mfma16(kf, qf[qt][ks], s[ct]);
        }
      }
      const bool full = (kb + 127 <= qaT) && (kb >= qaT + 15 - 511);
      float mx = -1e30f;
#pragma unroll
      for (int ct = 0; ct < 8; ++ct)
#pragma unroll
        for (int r = 0; r < 4; ++r) {
          float val = s[ct][r] * scale2;
          if (!full) {
            int key = kb + ct * 16 + lkg * 4 + r;
            bool vis = (key <= qq) && (key >= qq - 511);
            val = vis ? val : -1e30f;
          }
          s[ct][r] = val;
          mx = fmaxf(mx, val);
        }
      mx = fmaxf(mx, __shfl_xor(mx, 16));
      mx = fmaxf(mx, __shfl_xor(mx, 32));
      float nm = fmaxf(m_i[qt], mx);
      float alpha = exp2f(m_i[qt] - nm);
      m_i[qt] = nm;

      float ps = 0.f;
#pragma unroll
      for (int ct = 0; ct < 8; ++ct) {
        float p0 = exp2f(s[ct][0] - nm), p1 = exp2f(s[ct][1] - nm);
        float p2 = exp2f(s[ct][2] - nm), p3 = exp2f(s[ct][3] - nm);
        ps += (p0 + p1) + (p2 + p3);
        *(uint2*)&PT[w][lrow * 136 + ct * 16 + lkg * 4] =
            uint2{cvt_pk_bf16(p0, p1), cvt_pk_bf16(p2, p3)};
      }
      ps += __shfl_xor(ps, 16);
      ps += __shfl_xor(ps, 32);
      l_i[qt] = l_i[qt] * alpha + ps;

#pragma unroll
      for (int nt = 0; nt < 4; ++nt)
#pragma unroll
        for (int r = 0; r < 4; ++r) o[nt][qt][r] *= alpha;

#pragma unroll
      for (int kk = 0; kk < 4; ++kk) {
        short8 pf = *(const short8*)&PT[w][lrow * 136 + kk * 32 + lkg * 8];
#pragma unroll
        for (int nt = 0; nt < 4; ++nt) {
          short8 vf = *(const short8*)&VT[(nt * 16 + lrow) * 136 + kk * 32 + lkg * 8];
          o[nt][qt] = mfma16(vf, pf, o[nt][qt]);
        }
      }
    }
    nbuf ^= 1;
  }

#pragma unroll
  for (int qt = 0; qt < 2; ++qt) {
    const int qq = q0 + qt * 64 + w * 16 + lrow;
    const float inv = 1.0f / l_i[qt];
#pragma unroll
    for (int nt = 0; nt < 4; ++nt) {
      floatx4 ov = o[nt][qt];
      uint32_t lo = cvt_pk_bf16(ov[0] * inv, ov[1] * inv);
      uint32_t hi = cvt_pk_bf16(ov[2] * inv, ov[3] * inv);
      *(uint2*)&aout[(size_t)qq * 1024 + h * 64 + nt * 16 + lkg * 4] = uint2{lo, hi};
    }
  }
}

// ---------------------------------------------------------------------------
extern "C" void kernel_launch(void* const* d_in, const int* in_sizes, int n_in,
                              void* d_out, int out_size, void* d_ws, size_t ws_size,
                              hipStream_t stream) {
  const float* x = (const float*)d_in[0];
  const float* wq = (const float*)d_in[1];
  const float* wk = (const float*)d_in[2];
  const float* wv = (const float*)d_in[3];
  const float* wo = (const float*)d_in[4];

  char* ws = (char*)d_ws;
  unsigned short* Xb = (unsigned short*)(ws);                 // 8 MB
  unsigned short* Wqkv = (unsigned short*)(ws + (8u << 20));  // 6 MB
  unsigned short* Wob = (unsigned short*)(ws + (14u << 20));  // 2 MB
  unsigned short* QKV = (unsigned short*)(ws + (16u << 20));  // 24 MB
  unsigned short* AO = (unsigned short*)(ws + (40u << 20));   // 8 MB

  convert_pack<<<8192, 256, 0, stream>>>((const float4*)x, (const float4*)wq,
                                         (const float4*)wk, (const float4*)wv,
                                         (const float4*)wo, (ushort4*)Xb,
                                         (ushort4*)Wqkv, (ushort4*)Wob);
  gemm_bt<unsigned short><<<dim3(32, 24), 256, 0, stream>>>(Xb, Wqkv, QKV, 3072, 1024);
  attn_kernel<<<512, 256, 0, stream>>>(QKV, AO);
  gemm64<<<dim3(64, 8), 256, 0, stream>>>(AO, Wob, (float*)d_out, 1024, 1024);
}

// Round 2
// 195.110 us; speedup vs baseline: 1.0397x; 1.0397x over previous
//
#include <hip/hip_runtime.h>
#include <stdint.h>

#define AS1 __attribute__((address_space(1)))
#define AS3 __attribute__((address_space(3)))

typedef short short8 __attribute__((ext_vector_type(8)));
typedef unsigned short ushort8 __attribute__((ext_vector_type(8)));
typedef __bf16 bf16x8 __attribute__((ext_vector_type(8)));
typedef float floatx4 __attribute__((ext_vector_type(4)));

__device__ __forceinline__ floatx4 mfma16(short8 a, short8 b, floatx4 c) {
  return __builtin_amdgcn_mfma_f32_16x16x32_bf16(
      __builtin_bit_cast(bf16x8, a), __builtin_bit_cast(bf16x8, b), c, 0, 0, 0);
}

__device__ __forceinline__ unsigned short f2bf(float f) {
  uint32_t u = __builtin_bit_cast(uint32_t, f);
  u = (u + 0x7FFFu + ((u >> 16) & 1u)) >> 16;
  return (unsigned short)u;
}

// packed f32x2 -> bf16x2, 1 VALU instr for 2 values
__device__ __forceinline__ uint32_t cvt_pk_bf16(float a, float b) {
  uint32_t d;
  asm("v_cvt_pk_bf16_f32 %0, %1, %2" : "=v"(d) : "v"(a), "v"(b));
  return d;
}

// ---------------------------------------------------------------------------
// Convert/pack: x -> bf16, Wq|Wk|Wv -> Wqkv (3072x1024 bf16), Wo -> bf16.
// ---------------------------------------------------------------------------
__global__ __launch_bounds__(256) void convert_pack(
    const float4* __restrict__ x, const float4* __restrict__ wq,
    const float4* __restrict__ wk, const float4* __restrict__ wv,
    const float4* __restrict__ wo, ushort4* __restrict__ xb,
    ushort4* __restrict__ wqkvb, ushort4* __restrict__ wob) {
  int i = blockIdx.x * 256 + threadIdx.x;
  const float4* src;
  ushort4* dst;
  if (i < (1 << 20)) {
    src = x + i;
    dst = xb + i;
  } else {
    int t = i - (1 << 20);
    int r = t >> 18;
    int j = t & ((1 << 18) - 1);
    src = (r == 0 ? wq : r == 1 ? wk : r == 2 ? wv : wo) + j;
    dst = (r < 3) ? (wqkvb + (r << 18) + j) : (wob + j);
  }
  float4 v = *src;
  ushort4 o;
  o.x = f2bf(v.x);
  o.y = f2bf(v.y);
  o.z = f2bf(v.z);
  o.w = f2bf(v.w);
  *dst = o;
}

// ---------------------------------------------------------------------------
// GEMM 128x128 tile (QKV projection): C[M][N] = A[M][K] @ B[N][K]^T.
// Round-2 experiment: occupancy-PRESERVING 1-deep pipeline. BK=32 with
// double-buffer = 2 x 16 KB = 32 KB LDS total (same footprint as the proven
// 59us single-buffer BK=64 baseline, unlike round-1's 64 KB which halved
// co-residency). stage(t+1) issues before compute(t); the single
// __syncthreads per iter drains it after the ds_read+MFMA phase.
// XCD-compact supertile swizzle kept (mechanism-sound, measured harmless).
// ---------------------------------------------------------------------------
template <typename OutT>
__global__ __launch_bounds__(256) void gemm_bt(const unsigned short* __restrict__ A,
                                               const unsigned short* __restrict__ Bm,
                                               OutT* __restrict__ C, int N, int K) {
  __shared__ unsigned short lds[2][16 * 512];  // 2 x 16 KB (BK=32)
  const int tid = threadIdx.x;
  const int lane = tid & 63;
  const int w = tid >> 6;
  const int wr = w >> 1, wc = w & 1;

  // Swizzle for grid (32,24)=768: each XCD owns contiguous work chunks.
  const int lid = blockIdx.y * gridDim.x + blockIdx.x;
  const int xcd = lid & 7;
  const int wgid = xcd * 96 + (lid >> 3);  // 0..767, contiguous per XCD
  const int s = wgid >> 5, w5 = wgid & 31; // supertile 0..23, within 0..31
  const int mt = (s & 3) * 8 + (w5 & 7);   // 0..31
  const int nt = (s >> 2) * 4 + (w5 >> 3); // 0..23
  const int tm = mt * 128, tn = nt * 128;
  const int lrow = lane & 15;
  const int lk = (lane >> 4) * 8;

  floatx4 acc[4][4];
#pragma unroll
  for (int i = 0; i < 4; ++i)
#pragma unroll
    for (int j = 0; j < 4; ++j) acc[i][j] = floatx4{0.f, 0.f, 0.f, 0.f};

  // Stage one BK=32 K-slice: A rows tm..tm+127 (chunks 0-7), B rows
  // tn..tn+127 (chunks 8-15). Chunk = 16 rows x 32 cols = 1 KB, written
  // linearly by one global_load_lds (lane l -> row l&15, colgrp l>>4).
  auto stage = [&](int buf, int k0) {
#pragma unroll
    for (int c = w * 4; c < w * 4 + 4; ++c) {
      const unsigned short* g;
      if (c < 8) {
        g = A + (size_t)(tm + c * 16 + lrow) * K + (k0 + lk);
      } else {
        g = Bm + (size_t)(tn + (c - 8) * 16 + lrow) * K + (k0 + lk);
      }
      __builtin_amdgcn_global_load_lds((const AS1 uint32_t*)g,
                                       (AS3 uint32_t*)(&lds[buf][c * 512]), 16, 0, 0);
    }
  };

  stage(0, 0);
  __syncthreads();  // prologue loads landed (barrier drains vmcnt)

  const int T = K >> 5;  // 32
  for (int t = 0; t < T; ++t) {
    if (t + 1 < T) stage((t + 1) & 1, (t + 1) << 5);  // prefetch next K-slice
    const unsigned short* L = lds[t & 1];
    short8 af[4], bf[4];
#pragma unroll
    for (int i = 0; i < 4; ++i)
      af[i] = *(const short8*)&L[(wr * 4 + i) * 512 + lane * 8];
#pragma unroll
    for (int j = 0; j < 4; ++j)
      bf[j] = *(const short8*)&L[(8 + wc * 4 + j) * 512 + lane * 8];
#pragma unroll
    for (int i = 0; i < 4; ++i)
#pragma unroll
      for (int j = 0; j < 4; ++j) acc[i][j] = mfma16(af[i], bf[j], acc[i][j]);
    __syncthreads();  // readers of lds[t&1] done; stage(t+1) drained (landed)
  }

  const int r0 = (lane >> 4) * 4;
#pragma unroll
  for (int i = 0; i < 4; ++i)
#pragma unroll
    for (int j = 0; j < 4; ++j)
#pragma unroll
      for (int r = 0; r < 4; ++r) {
        int row = tm + wr * 64 + i * 16 + r0 + r;
        int col = tn + wc * 64 + j * 16 + lrow;
        float v = acc[i][j][r];
        if constexpr (sizeof(OutT) == 2)
          C[(size_t)row * N + col] = f2bf(v);
        else
          C[(size_t)row * N + col] = v;
      }
}

// ---------------------------------------------------------------------------
// GEMM 64x128 tile (output projection). Same occupancy-preserving BK=32
// double-buffer: 2 x 12 KB = 24 KB (same footprint as the original).
// ---------------------------------------------------------------------------
__global__ __launch_bounds__(256) void gemm64(const unsigned short* __restrict__ A,
                                              const unsigned short* __restrict__ Bm,
                                              float* __restrict__ C, int N, int K) {
  __shared__ unsigned short lds[2][12 * 512];  // A: chunks 0-3, B: 4-11
  const int tid = threadIdx.x;
  const int lane = tid & 63;
  const int w = tid >> 6;
  const int wr = w >> 1, wc = w & 1;

  const int lid = blockIdx.y * gridDim.x + blockIdx.x;
  const int xcd = lid & 7;
  const int wgid = xcd * 64 + (lid >> 3);  // 0..511, contiguous per XCD
  const int s = wgid >> 5, w5 = wgid & 31; // supertile 0..15, within 0..31
  const int mt = (s & 3) * 16 + (w5 & 15); // 0..63
  const int nt = (s >> 2) * 2 + (w5 >> 4); // 0..7
  const int tm = mt * 64, tn = nt * 128;
  const int lrow = lane & 15;
  const int lk = (lane >> 4) * 8;

  floatx4 acc[2][4];
#pragma unroll
  for (int i = 0; i < 2; ++i)
#pragma unroll
    for (int j = 0; j < 4; ++j) acc[i][j] = floatx4{0.f, 0.f, 0.f, 0.f};

  auto stage = [&](int buf, int k0) {
#pragma unroll
    for (int c = w * 3; c < w * 3 + 3; ++c) {
      const unsigned short* g;
      if (c < 4) {
        g = A + (size_t)(tm + c * 16 + lrow) * K + (k0 + lk);
      } else {
        g = Bm + (size_t)(tn + (c - 4) * 16 + lrow) * K + (k0 + lk);
      }
      __builtin_amdgcn_global_load_lds((const AS1 uint32_t*)g,
                                       (AS3 uint32_t*)(&lds[buf][c * 512]), 16, 0, 0);
    }
  };

  stage(0, 0);
  __syncthreads();

  const int T = K >> 5;  // 32
  for (int t = 0; t < T; ++t) {
    if (t + 1 < T) stage((t + 1) & 1, (t + 1) << 5);
    const unsigned short* L = lds[t & 1];
    short8 af[2], bf[4];
#pragma unroll
    for (int i = 0; i < 2; ++i)
      af[i] = *(const short8*)&L[(wr * 2 + i) * 512 + lane * 8];
#pragma unroll
    for (int j = 0; j < 4; ++j)
      bf[j] = *(const short8*)&L[(4 + wc * 4 + j) * 512 + lane * 8];
#pragma unroll
    for (int i = 0; i < 2; ++i)
#pragma unroll
      for (int j = 0; j < 4; ++j) acc[i][j] = mfma16(af[i], bf[j], acc[i][j]);
    __syncthreads();
  }

  const int r0 = (lane >> 4) * 4;
#pragma unroll
  for (int i = 0; i < 2; ++i)
#pragma unroll
    for (int j = 0; j < 4; ++j)
#pragma unroll
      for (int r = 0; r < 4; ++r) {
        int row = tm + (wr * 2 + i) * 16 + r0 + r;
        int col = tn + (wc * 4 + j) * 16 + lrow;
        C[(size_t)row * N + col] = acc[i][j][r];
      }
}

// ---------------------------------------------------------------------------
// Flash attention, S^T orientation, 128 q/WG, 128-key blocks + 16-key sink.
// (unchanged from the proven baseline)
// ---------------------------------------------------------------------------
__global__ __launch_bounds__(256) void attn_kernel(const unsigned short* __restrict__ qkv,
                                                   unsigned short* __restrict__ aout) {
  __shared__ unsigned short Klds[2][16 * 512];  // 2 x 16KB A-frag chunks
  __shared__ unsigned short VT[64 * 136];       // V^T [d][key], stride 136
  __shared__ unsigned short PT[4][16 * 136];    // per-wave P^T [q][key]

  const int tid = threadIdx.x;
  const int lane = tid & 63;
  const int w = tid >> 6;
  const int lrow = lane & 15;
  const int lkg = lane >> 4;

  const int i = blockIdx.x;
  const int half = i >> 8;
  const int j = (i >> 3) & 31;
  const int h = 2 * (i & 7) + half;
  const int qb = half ? (31 - j) : j;
  const int q0 = qb * 128;

  short8 qf[2][2];
#pragma unroll
  for (int qt = 0; qt < 2; ++qt)
#pragma unroll
    for (int ks = 0; ks < 2; ++ks)
      qf[qt][ks] = *(const short8*)&qkv[(size_t)(q0 + qt * 64 + w * 16 + lrow) * 3072 +
                                        h * 64 + ks * 32 + lkg * 8];

  float m_i[2], l_i[2];
  floatx4 o[4][2];
#pragma unroll
  for (int qt = 0; qt < 2; ++qt) {
    m_i[qt] = -1e30f;
    l_i[qt] = 0.f;
#pragma unroll
    for (int nt = 0; nt < 4; ++nt) o[nt][qt] = floatx4{0.f, 0.f, 0.f, 0.f};
  }

  const float scale2 = 0.125f * 1.44269504088896f;  // 1/sqrt(64) * log2(e)

  // ---- prologue: stage sink K/V; prefetch window block 0 ----
  if (w < 2) {  // sink K chunks 0,1 into Klds[0]
    const unsigned short* g = &qkv[(size_t)lrow * 3072 + 1024 + h * 64 + w * 32 + lkg * 8];
    __builtin_amdgcn_global_load_lds((const AS1 uint32_t*)g,
                                     (AS3 uint32_t*)(&Klds[0][w * 512]), 16, 0, 0);
  }
  {  // sink V^T keys 0..31 (PV spans 0..31; P=0 for 16..31)
    if (lane < 16) {
      const unsigned short* g0 = &qkv[(size_t)(2 * lane) * 3072 + 2048 + h * 64 + w * 16];
      ushort8 a0 = *(const ushort8*)g0;
      ushort8 a1 = *(const ushort8*)(g0 + 8);
      ushort8 b0 = *(const ushort8*)(g0 + 3072);
      ushort8 b1 = *(const ushort8*)(g0 + 3080);
      uint32_t* vt = (uint32_t*)VT;
#pragma unroll
      for (int dd = 0; dd < 8; ++dd) {
        vt[(w * 16 + dd) * 68 + lane] = (uint32_t)a0[dd] | ((uint32_t)b0[dd] << 16);
        vt[(w * 16 + 8 + dd) * 68 + lane] = (uint32_t)a1[dd] | ((uint32_t)b1[dd] << 16);
      }
    }
  }
  const int kb0 = (q0 - 511 < 16) ? 16 : (q0 - 511);
  // prefetch window block 0: K -> Klds[1], V -> registers
#pragma unroll
  for (int c = 0; c < 4; ++c) {
    int ch = w * 4 + c;
    int kt = ch >> 1, ks = ch & 1;
    const unsigned short* g =
        &qkv[(size_t)(kb0 + kt * 16 + lrow) * 3072 + 1024 + h * 64 + ks * 32 + lkg * 8];
    __builtin_amdgcn_global_load_lds((const AS1 uint32_t*)g,
                                     (AS3 uint32_t*)(&Klds[1][ch * 512]), 16, 0, 0);
  }
  ushort8 va0, va1, vb0, vb1;
  {
    const unsigned short* g0 = &qkv[(size_t)(kb0 + 2 * lane) * 3072 + 2048 + h * 64 + w * 16];
    va0 = *(const ushort8*)g0;
    va1 = *(const ushort8*)(g0 + 8);
    vb0 = *(const ushort8*)(g0 + 3072);
    vb1 = *(const ushort8*)(g0 + 3080);
  }
  __syncthreads();

  // ---- sink compute (keys 0..15; PV over 0..31 with P=0 padding) ----
#pragma unroll
  for (int qt = 0; qt < 2; ++qt) {
    const int qq = q0 + qt * 64 + w * 16 + lrow;
    floatx4 s0 = floatx4{0.f, 0.f, 0.f, 0.f};
#pragma unroll
    for (int ks = 0; ks < 2; ++ks) {
      short8 kf = *(const short8*)&Klds[0][ks * 512 + lane * 8];
      s0 = mfma16(kf, qf[qt][ks], s0);
    }
    float mx = -1e30f;
    float sv[4];
#pragma unroll
    for (int r = 0; r < 4; ++r) {
      int key = lkg * 4 + r;
      bool vis = (key <= qq) && ((key < 4) || (key >= qq - 511));
      sv[r] = vis ? s0[r] * scale2 : -1e30f;
      mx = fmaxf(mx, sv[r]);
    }
    mx = fmaxf(mx, __shfl_xor(mx, 16));
    mx = fmaxf(mx, __shfl_xor(mx, 32));
    m_i[qt] = mx;  // key 0 always visible -> finite
    float p0 = exp2f(sv[0] - mx), p1 = exp2f(sv[1] - mx);
    float p2 = exp2f(sv[2] - mx), p3 = exp2f(sv[3] - mx);
    float ps = (p0 + p1) + (p2 + p3);
    *(uint2*)&PT[w][lrow * 136 + lkg * 4] = uint2{cvt_pk_bf16(p0, p1), cvt_pk_bf16(p2, p3)};
    *(uint2*)&PT[w][lrow * 136 + 16 + lkg * 4] = uint2{0u, 0u};  // keys 16..31 = 0
    ps += __shfl_xor(ps, 16);
    ps += __shfl_xor(ps, 32);
    l_i[qt] = ps;
    short8 pf = *(const short8*)&PT[w][lrow * 136 + lkg * 8];
#pragma unroll
    for (int nt = 0; nt < 4; ++nt) {
      short8 vf = *(const short8*)&VT[(nt * 16 + lrow) * 136 + lkg * 8];
      o[nt][qt] = mfma16(vf, pf, o[nt][qt]);
    }
  }

  // ---- window blocks of 128 keys (pipelined) ----
  int nbuf = 1;
  for (int kb = kb0; kb < q0 + 128; kb += 128) {
    const bool hasnext = (kb + 128 < q0 + 128);
    __syncthreads();  // prev readers of VT done; this block's K/V prefetch drained (landed)
    {  // write V^T for this block from prefetched registers
      uint32_t* vt = (uint32_t*)VT;
#pragma unroll
      for (int dd = 0; dd < 8; ++dd) {
        vt[(w * 16 + dd) * 68 + lane] = (uint32_t)va0[dd] | ((uint32_t)vb0[dd] << 16);
        vt[(w * 16 + 8 + dd) * 68 + lane] = (uint32_t)va1[dd] | ((uint32_t)vb1[dd] << 16);
      }
    }
    __syncthreads();  // VT visible

    // issue prefetches for block n+1 (after the barrier so the drain above
    // never waits on them; they land during this block's compute)
    if (hasnext) {
      const int kn = kb + 128;
#pragma unroll
      for (int c = 0; c < 4; ++c) {
        int ch = w * 4 + c;
        int kt = ch >> 1, ks = ch & 1;
        const unsigned short* g =
            &qkv[(size_t)(kn + kt * 16 + lrow) * 3072 + 1024 + h * 64 + ks * 32 + lkg * 8];
        __builtin_amdgcn_global_load_lds((const AS1 uint32_t*)g,
                                         (AS3 uint32_t*)(&Klds[1 - nbuf][ch * 512]), 16, 0, 0);
      }
      const unsigned short* g0 = &qkv[(size_t)(kn + 2 * lane) * 3072 + 2048 + h * 64 + w * 16];
      va0 = *(const ushort8*)g0;
      va1 = *(const ushort8*)(g0 + 8);
      vb0 = *(const ushort8*)(g0 + 3072);
      vb1 = *(const ushort8*)(g0 + 3080);
    }

#pragma unroll
    for (int qt = 0; qt < 2; ++qt) {
      const int qaT = q0 + qt * 64 + w * 16;  // wave-uniform
      const int qq = qaT + lrow;
      floatx4 s[8];
#pragma unroll
      for (int ct = 0; ct < 8; ++ct) {
        s[ct] = floatx4{0.f, 0.f, 0.f, 0.f};
#pragma unroll
        for (int ks = 0; ks < 2; ++ks) {
          short8 kf = *(const short8*)&Klds[nbuf][(ct * 2 + ks) * 512 + lane * 8];
          s[ct] = mfma16(kf, qf[qt][ks], s[ct]);
        }
      }
      const bool full = (kb + 127 <= qaT) && (kb >= qaT + 15 - 511);
      float mx = -1e30f;
#pragma unroll
      for (int ct = 0; ct < 8; ++ct)
#pragma unroll
        for (int r = 0; r < 4; ++r) {
          float val = s[ct][r] * scale2;
          if (!full) {
            int key = kb + ct * 16 + lkg * 4 + r;
            bool vis = (key <= qq) && (key >= qq - 511);
            val = vis ? val : -1e30f;
          }
          s[ct][r] = val;
          mx = fmaxf(mx, val);
        }
      mx = fmaxf(mx, __shfl_xor(mx, 16));
      mx = fmaxf(mx, __shfl_xor(mx, 32));
      float nm = fmaxf(m_i[qt], mx);
      float alpha = exp2f(m_i[qt] - nm);
      m_i[qt] = nm;

      float ps = 0.f;
#pragma unroll
      for (int ct = 0; ct < 8; ++ct) {
        float p0 = exp2f(s[ct][0] - nm), p1 = exp2f(s[ct][1] - nm);
        float p2 = exp2f(s[ct][2] - nm), p3 = exp2f(s[ct][3] - nm);
        ps += (p0 + p1) + (p2 + p3);
        *(uint2*)&PT[w][lrow * 136 + ct * 16 + lkg * 4] =
            uint2{cvt_pk_bf16(p0, p1), cvt_pk_bf16(p2, p3)};
      }
      ps += __shfl_xor(ps, 16);
      ps += __shfl_xor(ps, 32);
      l_i[qt] = l_i[qt] * alpha + ps;

#pragma unroll
      for (int nt = 0; nt < 4; ++nt)
#pragma unroll
        for (int r = 0; r < 4; ++r) o[nt][qt][r] *= alpha;

#pragma unroll
      for (int kk = 0; kk < 4; ++kk) {
        short8 pf = *(const short8*)&PT[w][lrow * 136 + kk * 32 + lkg * 8];
#pragma unroll
        for (int nt = 0; nt < 4; ++nt) {
          short8 vf = *(const short8*)&VT[(nt * 16 + lrow) * 136 + kk * 32 + lkg * 8];
          o[nt][qt] = mfma16(vf, pf, o[nt][qt]);
        }
      }
    }
    nbuf ^= 1;
  }

#pragma unroll
  for (int qt = 0; qt < 2; ++qt) {
    const int qq = q0 + qt * 64 + w * 16 + lrow;
    const float inv = 1.0f / l_i[qt];
#pragma unroll
    for (int nt = 0; nt < 4; ++nt) {
      floatx4 ov = o[nt][qt];
      uint32_t lo = cvt_pk_bf16(ov[0] * inv, ov[1] * inv);
      uint32_t hi = cvt_pk_bf16(ov[2] * inv, ov[3] * inv);
      *(uint2*)&aout[(size_t)qq * 1024 + h * 64 + nt * 16 + lkg * 4] = uint2{lo, hi};
    }
  }
}

// ---------------------------------------------------------------------------
extern "C" void kernel_launch(void* const* d_in, const int* in_sizes, int n_in,
                              void* d_out, int out_size, void* d_ws, size_t ws_size,
                              hipStream_t stream) {
  const float* x = (const float*)d_in[0];
  const float* wq = (const float*)d_in[1];
  const float* wk = (const float*)d_in[2];
  const float* wv = (const float*)d_in[3];
  const float* wo = (const float*)d_in[4];

  char* ws = (char*)d_ws;
  unsigned short* Xb = (unsigned short*)(ws);                 // 8 MB
  unsigned short* Wqkv = (unsigned short*)(ws + (8u << 20));  // 6 MB
  unsigned short* Wob = (unsigned short*)(ws + (14u << 20));  // 2 MB
  unsigned short* QKV = (unsigned short*)(ws + (16u << 20));  // 24 MB
  unsigned short* AO = (unsigned short*)(ws + (40u << 20));   // 8 MB

  convert_pack<<<8192, 256, 0, stream>>>((const float4*)x, (const float4*)wq,
                                         (const float4*)wk, (const float4*)wv,
                                         (const float4*)wo, (ushort4*)Xb,
                                         (ushort4*)Wqkv, (ushort4*)Wob);
  gemm_bt<unsigned short><<<dim3(32, 24), 256, 0, stream>>>(Xb, Wqkv, QKV, 3072, 1024);
  attn_kernel<<<512, 256, 0, stream>>>(QKV, AO);
  gemm64<<<dim3(64, 8), 256, 0, stream>>>(AO, Wob, (float*)d_out, 1024, 1024);
}

// Round 3
// 193.388 us; speedup vs baseline: 1.0490x; 1.0089x over previous
//
#include <hip/hip_runtime.h>
#include <stdint.h>

#define AS1 __attribute__((address_space(1)))
#define AS3 __attribute__((address_space(3)))

typedef short short8 __attribute__((ext_vector_type(8)));
typedef unsigned short ushort8 __attribute__((ext_vector_type(8)));
typedef __bf16 bf16x8 __attribute__((ext_vector_type(8)));
typedef float floatx4 __attribute__((ext_vector_type(4)));

__device__ __forceinline__ floatx4 mfma16(short8 a, short8 b, floatx4 c) {
  return __builtin_amdgcn_mfma_f32_16x16x32_bf16(
      __builtin_bit_cast(bf16x8, a), __builtin_bit_cast(bf16x8, b), c, 0, 0, 0);
}

__device__ __forceinline__ unsigned short f2bf(float f) {
  uint32_t u = __builtin_bit_cast(uint32_t, f);
  u = (u + 0x7FFFu + ((u >> 16) & 1u)) >> 16;
  return (unsigned short)u;
}

// packed f32x2 -> bf16x2, 1 VALU instr for 2 values
__device__ __forceinline__ uint32_t cvt_pk_bf16(float a, float b) {
  uint32_t d;
  asm("v_cvt_pk_bf16_f32 %0, %1, %2" : "=v"(d) : "v"(a), "v"(b));
  return d;
}

// ---------------------------------------------------------------------------
// Convert/pack: x -> bf16, Wq|Wk|Wv -> Wqkv (3072x1024 bf16), Wo -> bf16.
// ---------------------------------------------------------------------------
__global__ __launch_bounds__(256) void convert_pack(
    const float4* __restrict__ x, const float4* __restrict__ wq,
    const float4* __restrict__ wk, const float4* __restrict__ wv,
    const float4* __restrict__ wo, ushort4* __restrict__ xb,
    ushort4* __restrict__ wqkvb, ushort4* __restrict__ wob) {
  int i = blockIdx.x * 256 + threadIdx.x;
  const float4* src;
  ushort4* dst;
  if (i < (1 << 20)) {
    src = x + i;
    dst = xb + i;
  } else {
    int t = i - (1 << 20);
    int r = t >> 18;
    int j = t & ((1 << 18) - 1);
    src = (r == 0 ? wq : r == 1 ? wk : r == 2 ? wv : wo) + j;
    dst = (r < 3) ? (wqkvb + (r << 18) + j) : (wob + j);
  }
  float4 v = *src;
  ushort4 o;
  o.x = f2bf(v.x);
  o.y = f2bf(v.y);
  o.z = f2bf(v.z);
  o.w = f2bf(v.w);
  *dst = o;
}

// ---------------------------------------------------------------------------
// GEMM 128x128 tile (QKV projection): C[M][N] = A[M][K] @ B[N][K]^T.
// Round-3: counted-vmcnt pipeline (T4). Diagnosis: __syncthreads' implicit
// vmcnt(0) drained the JUST-ISSUED prefetch every iter -> fixed ~4000cy/iter
// latency path (54us). Fix: 3 x 16KB buffers (depth-2 prefetch), one raw
// s_barrier per iter, s_waitcnt vmcnt(4) (= leave next stage's 4 loads/wave
// in flight). Final iter peeled with vmcnt(0). 48KB LDS keeps 3 WG/CU.
// Safety: buf (t+2)%3 was last read in iter t-1, completed by all waves
// before barrier t; sched_barrier(0) fences ds_read hoisting (rule #18).
// ---------------------------------------------------------------------------
template <typename OutT>
__global__ __launch_bounds__(256) void gemm_bt(const unsigned short* __restrict__ A,
                                               const unsigned short* __restrict__ Bm,
                                               OutT* __restrict__ C, int N, int K) {
  __shared__ unsigned short lds[3][16 * 512];  // 3 x 16 KB (BK=32)
  const int tid = threadIdx.x;
  const int lane = tid & 63;
  const int w = tid >> 6;
  const int wr = w >> 1, wc = w & 1;

  // XCD-compact supertile swizzle for grid (32,24)=768 (bijective).
  const int lid = blockIdx.y * gridDim.x + blockIdx.x;
  const int xcd = lid & 7;
  const int wgid = xcd * 96 + (lid >> 3);  // 0..767, contiguous per XCD
  const int s = wgid >> 5, w5 = wgid & 31; // supertile 0..23, within 0..31
  const int mt = (s & 3) * 8 + (w5 & 7);   // 0..31
  const int nt = (s >> 2) * 4 + (w5 >> 3); // 0..23
  const int tm = mt * 128, tn = nt * 128;
  const int lrow = lane & 15;
  const int lk = (lane >> 4) * 8;

  floatx4 acc[4][4];
#pragma unroll
  for (int i = 0; i < 4; ++i)
#pragma unroll
    for (int j = 0; j < 4; ++j) acc[i][j] = floatx4{0.f, 0.f, 0.f, 0.f};

  // Stage one BK=32 K-slice: A rows tm..tm+127 (chunks 0-7), B rows
  // tn..tn+127 (chunks 8-15). 4 global_load_lds per wave per stage.
  auto stage = [&](unsigned short* buf, int k0) {
#pragma unroll
    for (int c = w * 4; c < w * 4 + 4; ++c) {
      const unsigned short* g;
      if (c < 8) {
        g = A + (size_t)(tm + c * 16 + lrow) * K + (k0 + lk);
      } else {
        g = Bm + (size_t)(tn + (c - 8) * 16 + lrow) * K + (k0 + lk);
      }
      __builtin_amdgcn_global_load_lds((const AS1 uint32_t*)g,
                                       (AS3 uint32_t*)(buf + c * 512), 16, 0, 0);
    }
  };

  auto compute = [&](const unsigned short* L) {
    short8 af[4], bf[4];
#pragma unroll
    for (int i = 0; i < 4; ++i)
      af[i] = *(const short8*)&L[(wr * 4 + i) * 512 + lane * 8];
#pragma unroll
    for (int j = 0; j < 4; ++j)
      bf[j] = *(const short8*)&L[(8 + wc * 4 + j) * 512 + lane * 8];
#pragma unroll
    for (int i = 0; i < 4; ++i)
#pragma unroll
      for (int j = 0; j < 4; ++j) acc[i][j] = mfma16(af[i], bf[j], acc[i][j]);
  };

  stage(lds[0], 0);
  stage(lds[1], 32);

  const int T = K >> 5;  // 32
  int bt = 0;            // t % 3
  for (int t = 0; t < T - 1; ++t) {
    // wait for stage t (own wave's oldest 4); leave stage t+1's 4 in flight
    asm volatile("s_waitcnt vmcnt(4)" ::: "memory");
    __builtin_amdgcn_sched_barrier(0);
    __builtin_amdgcn_s_barrier();  // cross-wave: all chunks of stage t in LDS
    __builtin_amdgcn_sched_barrier(0);
    if (t + 2 < T) {
      int b2 = (bt + 2 >= 3) ? bt - 1 : bt + 2;
      stage(lds[b2], (t + 2) << 5);  // issue early: lands under compute
    }
    compute(lds[bt]);
    bt = (bt + 1 == 3) ? 0 : bt + 1;
  }
  // peeled final iteration: only stage T-1 outstanding
  asm volatile("s_waitcnt vmcnt(0)" ::: "memory");
  __builtin_amdgcn_sched_barrier(0);
  __builtin_amdgcn_s_barrier();
  __builtin_amdgcn_sched_barrier(0);
  compute(lds[bt]);

  const int r0 = (lane >> 4) * 4;
#pragma unroll
  for (int i = 0; i < 4; ++i)
#pragma unroll
    for (int j = 0; j < 4; ++j)
#pragma unroll
      for (int r = 0; r < 4; ++r) {
        int row = tm + wr * 64 + i * 16 + r0 + r;
        int col = tn + wc * 64 + j * 16 + lrow;
        float v = acc[i][j][r];
        if constexpr (sizeof(OutT) == 2)
          C[(size_t)row * N + col] = f2bf(v);
        else
          C[(size_t)row * N + col] = v;
      }
}

// ---------------------------------------------------------------------------
// GEMM 64x128 tile (output projection). Same counted-vmcnt pipeline:
// 3 x 12 KB buffers, 3 loads/wave/stage -> vmcnt(3) in steady state.
// ---------------------------------------------------------------------------
__global__ __launch_bounds__(256) void gemm64(const unsigned short* __restrict__ A,
                                              const unsigned short* __restrict__ Bm,
                                              float* __restrict__ C, int N, int K) {
  __shared__ unsigned short lds[3][12 * 512];  // A: chunks 0-3, B: 4-11
  const int tid = threadIdx.x;
  const int lane = tid & 63;
  const int w = tid >> 6;
  const int wr = w >> 1, wc = w & 1;

  const int lid = blockIdx.y * gridDim.x + blockIdx.x;
  const int xcd = lid & 7;
  const int wgid = xcd * 64 + (lid >> 3);  // 0..511, contiguous per XCD
  const int s = wgid >> 5, w5 = wgid & 31; // supertile 0..15, within 0..31
  const int mt = (s & 3) * 16 + (w5 & 15); // 0..63
  const int nt = (s >> 2) * 2 + (w5 >> 4); // 0..7
  const int tm = mt * 64, tn = nt * 128;
  const int lrow = lane & 15;
  const int lk = (lane >> 4) * 8;

  floatx4 acc[2][4];
#pragma unroll
  for (int i = 0; i < 2; ++i)
#pragma unroll
    for (int j = 0; j < 4; ++j) acc[i][j] = floatx4{0.f, 0.f, 0.f, 0.f};

  auto stage = [&](unsigned short* buf, int k0) {
#pragma unroll
    for (int c = w * 3; c < w * 3 + 3; ++c) {
      const unsigned short* g;
      if (c < 4) {
        g = A + (size_t)(tm + c * 16 + lrow) * K + (k0 + lk);
      } else {
        g = Bm + (size_t)(tn + (c - 4) * 16 + lrow) * K + (k0 + lk);
      }
      __builtin_amdgcn_global_load_lds((const AS1 uint32_t*)g,
                                       (AS3 uint32_t*)(buf + c * 512), 16, 0, 0);
    }
  };

  auto compute = [&](const unsigned short* L) {
    short8 af[2], bf[4];
#pragma unroll
    for (int i = 0; i < 2; ++i)
      af[i] = *(const short8*)&L[(wr * 2 + i) * 512 + lane * 8];
#pragma unroll
    for (int j = 0; j < 4; ++j)
      bf[j] = *(const short8*)&L[(4 + wc * 4 + j) * 512 + lane * 8];
#pragma unroll
    for (int i = 0; i < 2; ++i)
#pragma unroll
      for (int j = 0; j < 4; ++j) acc[i][j] = mfma16(af[i], bf[j], acc[i][j]);
  };

  stage(lds[0], 0);
  stage(lds[1], 32);

  const int T = K >> 5;  // 32
  int bt = 0;
  for (int t = 0; t < T - 1; ++t) {
    asm volatile("s_waitcnt vmcnt(3)" ::: "memory");
    __builtin_amdgcn_sched_barrier(0);
    __builtin_amdgcn_s_barrier();
    __builtin_amdgcn_sched_barrier(0);
    if (t + 2 < T) {
      int b2 = (bt + 2 >= 3) ? bt - 1 : bt + 2;
      stage(lds[b2], (t + 2) << 5);
    }
    compute(lds[bt]);
    bt = (bt + 1 == 3) ? 0 : bt + 1;
  }
  asm volatile("s_waitcnt vmcnt(0)" ::: "memory");
  __builtin_amdgcn_sched_barrier(0);
  __builtin_amdgcn_s_barrier();
  __builtin_amdgcn_sched_barrier(0);
  compute(lds[bt]);

  const int r0 = (lane >> 4) * 4;
#pragma unroll
  for (int i = 0; i < 2; ++i)
#pragma unroll
    for (int j = 0; j < 4; ++j)
#pragma unroll
      for (int r = 0; r < 4; ++r) {
        int row = tm + (wr * 2 + i) * 16 + r0 + r;
        int col = tn + (wc * 4 + j) * 16 + lrow;
        C[(size_t)row * N + col] = acc[i][j][r];
      }
}

// ---------------------------------------------------------------------------
// Flash attention, S^T orientation, 128 q/WG, 128-key blocks + 16-key sink.
// (unchanged from the proven baseline)
// ---------------------------------------------------------------------------
__global__ __launch_bounds__(256) void attn_kernel(const unsigned short* __restrict__ qkv,
                                                   unsigned short* __restrict__ aout) {
  __shared__ unsigned short Klds[2][16 * 512];  // 2 x 16KB A-frag chunks
  __shared__ unsigned short VT[64 * 136];       // V^T [d][key], stride 136
  __shared__ unsigned short PT[4][16 * 136];    // per-wave P^T [q][key]

  const int tid = threadIdx.x;
  const int lane = tid & 63;
  const int w = tid >> 6;
  const int lrow = lane & 15;
  const int lkg = lane >> 4;

  const int i = blockIdx.x;
  const int half = i >> 8;
  const int j = (i >> 3) & 31;
  const int h = 2 * (i & 7) + half;
  const int qb = half ? (31 - j) : j;
  const int q0 = qb * 128;

  short8 qf[2][2];
#pragma unroll
  for (int qt = 0; qt < 2; ++qt)
#pragma unroll
    for (int ks = 0; ks < 2; ++ks)
      qf[qt][ks] = *(const short8*)&qkv[(size_t)(q0 + qt * 64 + w * 16 + lrow) * 3072 +
                                        h * 64 + ks * 32 + lkg * 8];

  float m_i[2], l_i[2];
  floatx4 o[4][2];
#pragma unroll
  for (int qt = 0; qt < 2; ++qt) {
    m_i[qt] = -1e30f;
    l_i[qt] = 0.f;
#pragma unroll
    for (int nt = 0; nt < 4; ++nt) o[nt][qt] = floatx4{0.f, 0.f, 0.f, 0.f};
  }

  const float scale2 = 0.125f * 1.44269504088896f;  // 1/sqrt(64) * log2(e)

  // ---- prologue: stage sink K/V; prefetch window block 0 ----
  if (w < 2) {  // sink K chunks 0,1 into Klds[0]
    const unsigned short* g = &qkv[(size_t)lrow * 3072 + 1024 + h * 64 + w * 32 + lkg * 8];
    __builtin_amdgcn_global_load_lds((const AS1 uint32_t*)g,
                                     (AS3 uint32_t*)(&Klds[0][w * 512]), 16, 0, 0);
  }
  {  // sink V^T keys 0..31 (PV spans 0..31; P=0 for 16..31)
    if (lane < 16) {
      const unsigned short* g0 = &qkv[(size_t)(2 * lane) * 3072 + 2048 + h * 64 + w * 16];
      ushort8 a0 = *(const ushort8*)g0;
      ushort8 a1 = *(const ushort8*)(g0 + 8);
      ushort8 b0 = *(const ushort8*)(g0 + 3072);
      ushort8 b1 = *(const ushort8*)(g0 + 3080);
      uint32_t* vt = (uint32_t*)VT;
#pragma unroll
      for (int dd = 0; dd < 8; ++dd) {
        vt[(w * 16 + dd) * 68 + lane] = (uint32_t)a0[dd] | ((uint32_t)b0[dd] << 16);
        vt[(w * 16 + 8 + dd) * 68 + lane] = (uint32_t)a1[dd] | ((uint32_t)b1[dd] << 16);
      }
    }
  }
  const int kb0 = (q0 - 511 < 16) ? 16 : (q0 - 511);
  // prefetch window block 0: K -> Klds[1], V -> registers
#pragma unroll
  for (int c = 0; c < 4; ++c) {
    int ch = w * 4 + c;
    int kt = ch >> 1, ks = ch & 1;
    const unsigned short* g =
        &qkv[(size_t)(kb0 + kt * 16 + lrow) * 3072 + 1024 + h * 64 + ks * 32 + lkg * 8];
    __builtin_amdgcn_global_load_lds((const AS1 uint32_t*)g,
                                     (AS3 uint32_t*)(&Klds[1][ch * 512]), 16, 0, 0);
  }
  ushort8 va0, va1, vb0, vb1;
  {
    const unsigned short* g0 = &qkv[(size_t)(kb0 + 2 * lane) * 3072 + 2048 + h * 64 + w * 16];
    va0 = *(const ushort8*)g0;
    va1 = *(const ushort8*)(g0 + 8);
    vb0 = *(const ushort8*)(g0 + 3072);
    vb1 = *(const ushort8*)(g0 + 3080);
  }
  __syncthreads();

  // ---- sink compute (keys 0..15; PV over 0..31 with P=0 padding) ----
#pragma unroll
  for (int qt = 0; qt < 2; ++qt) {
    const int qq = q0 + qt * 64 + w * 16 + lrow;
    floatx4 s0 = floatx4{0.f, 0.f, 0.f, 0.f};
#pragma unroll
    for (int ks = 0; ks < 2; ++ks) {
      short8 kf = *(const short8*)&Klds[0][ks * 512 + lane * 8];
      s0 = mfma16(kf, qf[qt][ks], s0);
    }
    float mx = -1e30f;
    float sv[4];
#pragma unroll
    for (int r = 0; r < 4; ++r) {
      int key = lkg * 4 + r;
      bool vis = (key <= qq) && ((key < 4) || (key >= qq - 511));
      sv[r] = vis ? s0[r] * scale2 : -1e30f;
      mx = fmaxf(mx, sv[r]);
    }
    mx = fmaxf(mx, __shfl_xor(mx, 16));
    mx = fmaxf(mx, __shfl_xor(mx, 32));
    m_i[qt] = mx;  // key 0 always visible -> finite
    float p0 = exp2f(sv[0] - mx), p1 = exp2f(sv[1] - mx);
    float p2 = exp2f(sv[2] - mx), p3 = exp2f(sv[3] - mx);
    float ps = (p0 + p1) + (p2 + p3);
    *(uint2*)&PT[w][lrow * 136 + lkg * 4] = uint2{cvt_pk_bf16(p0, p1), cvt_pk_bf16(p2, p3)};
    *(uint2*)&PT[w][lrow * 136 + 16 + lkg * 4] = uint2{0u, 0u};  // keys 16..31 = 0
    ps += __shfl_xor(ps, 16);
    ps += __shfl_xor(ps, 32);
    l_i[qt] = ps;
    short8 pf = *(const short8*)&PT[w][lrow * 136 + lkg * 8];
#pragma unroll
    for (int nt = 0; nt < 4; ++nt) {
      short8 vf = *(const short8*)&VT[(nt * 16 + lrow) * 136 + lkg * 8];
      o[nt][qt] = mfma16(vf, pf, o[nt][qt]);
    }
  }

  // ---- window blocks of 128 keys (pipelined) ----
  int nbuf = 1;
  for (int kb = kb0; kb < q0 + 128; kb += 128) {
    const bool hasnext = (kb + 128 < q0 + 128);
    __syncthreads();  // prev readers of VT done; this block's K/V prefetch drained (landed)
    {  // write V^T for this block from prefetched registers
      uint32_t* vt = (uint32_t*)VT;
#pragma unroll
      for (int dd = 0; dd < 8; ++dd) {
        vt[(w * 16 + dd) * 68 + lane] = (uint32_t)va0[dd] | ((uint32_t)vb0[dd] << 16);
        vt[(w * 16 + 8 + dd) * 68 + lane] = (uint32_t)va1[dd] | ((uint32_t)vb1[dd] << 16);
      }
    }
    __syncthreads();  // VT visible

    // issue prefetches for block n+1 (after the barrier so the drain above
    // never waits on them; they land during this block's compute)
    if (hasnext) {
      const int kn = kb + 128;
#pragma unroll
      for (int c = 0; c < 4; ++c) {
        int ch = w * 4 + c;
        int kt = ch >> 1, ks = ch & 1;
        const unsigned short* g =
            &qkv[(size_t)(kn + kt * 16 + lrow) * 3072 + 1024 + h * 64 + ks * 32 + lkg * 8];
        __builtin_amdgcn_global_load_lds((const AS1 uint32_t*)g,
                                         (AS3 uint32_t*)(&Klds[1 - nbuf][ch * 512]), 16, 0, 0);
      }
      const unsigned short* g0 = &qkv[(size_t)(kn + 2 * lane) * 3072 + 2048 + h * 64 + w * 16];
      va0 = *(const ushort8*)g0;
      va1 = *(const ushort8*)(g0 + 8);
      vb0 = *(const ushort8*)(g0 + 3072);
      vb1 = *(const ushort8*)(g0 + 3080);
    }

#pragma unroll
    for (int qt = 0; qt < 2; ++qt) {
      const int qaT = q0 + qt * 64 + w * 16;  // wave-uniform
      const int qq = qaT + lrow;
      floatx4 s[8];
#pragma unroll
      for (int ct = 0; ct < 8; ++ct) {
        s[ct] = floatx4{0.f, 0.f, 0.f, 0.f};
#pragma unroll
        for (int ks = 0; ks < 2; ++ks) {
          short8 kf = *(const short8*)&Klds[nbuf][(ct * 2 + ks) * 512 + lane * 8];
          s[ct] = mfma16(kf, qf[qt][ks], s[ct]);
        }
      }
      const bool full = (kb + 127 <= qaT) && (kb >= qaT + 15 - 511);
      float mx = -1e30f;
#pragma unroll
      for (int ct = 0; ct < 8; ++ct)
#pragma unroll
        for (int r = 0; r < 4; ++r) {
          float val = s[ct][r] * scale2;
          if (!full) {
            int key = kb + ct * 16 + lkg * 4 + r;
            bool vis = (key <= qq) && (key >= qq - 511);
            val = vis ? val : -1e30f;
          }
          s[ct][r] = val;
          mx = fmaxf(mx, val);
        }
      mx = fmaxf(mx, __shfl_xor(mx, 16));
      mx = fmaxf(mx, __shfl_xor(mx, 32));
      float nm = fmaxf(m_i[qt], mx);
      float alpha = exp2f(m_i[qt] - nm);
      m_i[qt] = nm;

      float ps = 0.f;
#pragma unroll
      for (int ct = 0; ct < 8; ++ct) {
        float p0 = exp2f(s[ct][0] - nm), p1 = exp2f(s[ct][1] - nm);
        float p2 = exp2f(s[ct][2] - nm), p3 = exp2f(s[ct][3] - nm);
        ps += (p0 + p1) + (p2 + p3);
        *(uint2*)&PT[w][lrow * 136 + ct * 16 + lkg * 4] =
            uint2{cvt_pk_bf16(p0, p1), cvt_pk_bf16(p2, p3)};
      }
      ps += __shfl_xor(ps, 16);
      ps += __shfl_xor(ps, 32);
      l_i[qt] = l_i[qt] * alpha + ps;

#pragma unroll
      for (int nt = 0; nt < 4; ++nt)
#pragma unroll
        for (int r = 0; r < 4; ++r) o[nt][qt][r] *= alpha;

#pragma unroll
      for (int kk = 0; kk < 4; ++kk) {
        short8 pf = *(const short8*)&PT[w][lrow * 136 + kk * 32 + lkg * 8];
#pragma unroll
        for (int nt = 0; nt < 4; ++nt) {
          short8 vf = *(const short8*)&VT[(nt * 16 + lrow) * 136 + kk * 32 + lkg * 8];
          o[nt][qt] = mfma16(vf, pf, o[nt][qt]);
        }
      }
    }
    nbuf ^= 1;
  }

#pragma unroll
  for (int qt = 0; qt < 2; ++qt) {
    const int qq = q0 + qt * 64 + w * 16 + lrow;
    const float inv = 1.0f / l_i[qt];
#pragma unroll
    for (int nt = 0; nt < 4; ++nt) {
      floatx4 ov = o[nt][qt];
      uint32_t lo = cvt_pk_bf16(ov[0] * inv, ov[1] * inv);
      uint32_t hi = cvt_pk_bf16(ov[2] * inv, ov[3] * inv);
      *(uint2*)&aout[(size_t)qq * 1024 + h * 64 + nt * 16 + lkg * 4] = uint2{lo, hi};
    }
  }
}

// ---------------------------------------------------------------------------
extern "C" void kernel_launch(void* const* d_in, const int* in_sizes, int n_in,
                              void* d_out, int out_size, void* d_ws, size_t ws_size,
                              hipStream_t stream) {
  const float* x = (const float*)d_in[0];
  const float* wq = (const float*)d_in[1];
  const float* wk = (const float*)d_in[2];
  const float* wv = (const float*)d_in[3];
  const float* wo = (const float*)d_in[4];

  char* ws = (char*)d_ws;
  unsigned short* Xb = (unsigned short*)(ws);                 // 8 MB
  unsigned short* Wqkv = (unsigned short*)(ws + (8u << 20));  // 6 MB
  unsigned short* Wob = (unsigned short*)(ws + (14u << 20));  // 2 MB
  unsigned short* QKV = (unsigned short*)(ws + (16u << 20));  // 24 MB
  unsigned short* AO = (unsigned short*)(ws + (40u << 20));   // 8 MB

  convert_pack<<<8192, 256, 0, stream>>>((const float4*)x, (const float4*)wq,
                                         (const float4*)wk, (const float4*)wv,
                                         (const float4*)wo, (ushort4*)Xb,
                                         (ushort4*)Wqkv, (ushort4*)Wob);
  gemm_bt<unsigned short><<<dim3(32, 24), 256, 0, stream>>>(Xb, Wqkv, QKV, 3072, 1024);
  attn_kernel<<<512, 256, 0, stream>>>(QKV, AO);
  gemm64<<<dim3(64, 8), 256, 0, stream>>>(AO, Wob, (float*)d_out, 1024, 1024);
}

// Round 4
// 171.832 us; speedup vs baseline: 1.1805x; 1.1254x over previous
//
#include <hip/hip_runtime.h>
#include <stdint.h>

#define AS1 __attribute__((address_space(1)))
#define AS3 __attribute__((address_space(3)))

typedef short short8 __attribute__((ext_vector_type(8)));
typedef unsigned short ushort8 __attribute__((ext_vector_type(8)));
typedef __bf16 bf16x8 __attribute__((ext_vector_type(8)));
typedef float floatx4 __attribute__((ext_vector_type(4)));

__device__ __forceinline__ floatx4 mfma16(short8 a, short8 b, floatx4 c) {
  return __builtin_amdgcn_mfma_f32_16x16x32_bf16(
      __builtin_bit_cast(bf16x8, a), __builtin_bit_cast(bf16x8, b), c, 0, 0, 0);
}

__device__ __forceinline__ unsigned short f2bf(float f) {
  uint32_t u = __builtin_bit_cast(uint32_t, f);
  u = (u + 0x7FFFu + ((u >> 16) & 1u)) >> 16;
  return (unsigned short)u;
}

// packed f32x2 -> bf16x2, 1 VALU instr for 2 values
__device__ __forceinline__ uint32_t cvt_pk_bf16(float a, float b) {
  uint32_t d;
  asm("v_cvt_pk_bf16_f32 %0, %1, %2" : "=v"(d) : "v"(a), "v"(b));
  return d;
}

// ---------------------------------------------------------------------------
// Convert/pack v2: emits STAGING-TILED layouts so every gemm global_load_lds
// reads a contiguous lane-linear 1-KB block (8 full 128B lines) instead of
// 16 rows x 64B at 2-KB stride (half-utilized lines; suspected cause of the
// pinned ~11.5 B/cyc/CU staging rate across 3 pipeline variants).
// Tiled offset for element (row,col) of a matrix with 128-row tiles, BK=32:
//   blk = (rt*32 + col/32)*8 + (row/16)%8   [rt = row/128]
//   off = blk*512 + ((col%32)/8*16 + row%16)*8 + col%8   (ushort units)
// which makes stage addr = base + blk*512 + lane*8 with the SAME LDS chunk
// layout as before (lane -> row lane&15, colgroup lane>>4).
// ---------------------------------------------------------------------------
__device__ __forceinline__ size_t tiled_off(int row, int col) {
  int rt = row >> 7, c8 = (row >> 4) & 7, rr = row & 15;
  int t = col >> 5, lh = (col >> 3) & 3, e = col & 7;
  return ((size_t)((rt * 32 + t) * 8 + c8) << 9) + (lh * 16 + rr) * 8 + e;
}

__global__ __launch_bounds__(256) void convert_pack(
    const float4* __restrict__ x, const float4* __restrict__ wq,
    const float4* __restrict__ wk, const float4* __restrict__ wv,
    const float4* __restrict__ wo, unsigned short* __restrict__ xb,
    unsigned short* __restrict__ wqkvb, unsigned short* __restrict__ wob) {
  int i = blockIdx.x * 256 + threadIdx.x;  // 1M threads, 8 f32 each
  const float4* src;
  unsigned short* dstbase;
  int row, cb;
  if (i < (1 << 19)) {  // x: 4096x1024
    row = i >> 7;
    cb = i & 127;
    src = x + row * 256 + cb * 2;
    dstbase = xb + tiled_off(row, cb * 8);
  } else if (i < 917504) {  // Wq|Wk|Wv -> Wqkv_t rows 0..3071
    int j = i - (1 << 19);
    int r = j >> 17;
    int jj = j & 131071;
    int rw = jj >> 7;
    cb = jj & 127;
    src = (r == 0 ? wq : r == 1 ? wk : wv) + rw * 256 + cb * 2;
    row = r * 1024 + rw;
    dstbase = wqkvb + tiled_off(row, cb * 8);
  } else {  // Wo: 1024x1024
    int j = i - 917504;
    row = j >> 7;
    cb = j & 127;
    src = wo + row * 256 + cb * 2;
    dstbase = wob + tiled_off(row, cb * 8);
  }
  float4 a = src[0], b = src[1];
  ushort8 o;
  o[0] = f2bf(a.x); o[1] = f2bf(a.y); o[2] = f2bf(a.z); o[3] = f2bf(a.w);
  o[4] = f2bf(b.x); o[5] = f2bf(b.y); o[6] = f2bf(b.z); o[7] = f2bf(b.w);
  *(ushort8*)dstbase = o;  // tiled_off(row, 8-aligned col) is 8-aligned
}

// ---------------------------------------------------------------------------
// GEMM 128x128 tile (QKV projection): C[M][N] = A[M][K] @ B[N][K]^T.
// A and B are in staging-tiled layout (see convert_pack): each chunk load is
// a contiguous 1-KB lane-linear read. Pipeline: 3 x 16KB buffers, depth-2
// prefetch, counted vmcnt(4), raw s_barrier (round-3 structure, kept).
// ---------------------------------------------------------------------------
template <typename OutT>
__global__ __launch_bounds__(256) void gemm_bt(const unsigned short* __restrict__ A,
                                               const unsigned short* __restrict__ Bm,
                                               OutT* __restrict__ C, int N, int K) {
  __shared__ unsigned short lds[3][16 * 512];  // 3 x 16 KB (BK=32)
  const int tid = threadIdx.x;
  const int lane = tid & 63;
  const int w = tid >> 6;
  const int wr = w >> 1, wc = w & 1;

  // XCD-compact supertile swizzle for grid (32,24)=768 (bijective).
  const int lid = blockIdx.y * gridDim.x + blockIdx.x;
  const int xcd = lid & 7;
  const int wgid = xcd * 96 + (lid >> 3);  // 0..767, contiguous per XCD
  const int s = wgid >> 5, w5 = wgid & 31; // supertile 0..23, within 0..31
  const int mt = (s & 3) * 8 + (w5 & 7);   // 0..31
  const int nt = (s >> 2) * 4 + (w5 >> 3); // 0..23
  const int tm = mt * 128, tn = nt * 128;
  const int lrow = lane & 15;

  floatx4 acc[4][4];
#pragma unroll
  for (int i = 0; i < 4; ++i)
#pragma unroll
    for (int j = 0; j < 4; ++j) acc[i][j] = floatx4{0.f, 0.f, 0.f, 0.f};

  // Tiled staging: chunk c of K-step t is contiguous at blk*1KB.
  auto stage = [&](unsigned short* buf, int t) {
#pragma unroll
    for (int c = w * 4; c < w * 4 + 4; ++c) {
      const unsigned short* g;
      if (c < 8)
        g = A + ((size_t)((mt * 32 + t) * 8 + c) << 9) + lane * 8;
      else
        g = Bm + ((size_t)((nt * 32 + t) * 8 + (c - 8)) << 9) + lane * 8;
      __builtin_amdgcn_global_load_lds((const AS1 uint32_t*)g,
                                       (AS3 uint32_t*)(buf + c * 512), 16, 0, 0);
    }
  };

  auto compute = [&](const unsigned short* L) {
    short8 af[4], bf[4];
#pragma unroll
    for (int i = 0; i < 4; ++i)
      af[i] = *(const short8*)&L[(wr * 4 + i) * 512 + lane * 8];
#pragma unroll
    for (int j = 0; j < 4; ++j)
      bf[j] = *(const short8*)&L[(8 + wc * 4 + j) * 512 + lane * 8];
#pragma unroll
    for (int i = 0; i < 4; ++i)
#pragma unroll
      for (int j = 0; j < 4; ++j) acc[i][j] = mfma16(af[i], bf[j], acc[i][j]);
  };

  stage(lds[0], 0);
  stage(lds[1], 1);

  const int T = K >> 5;  // 32
  int bt = 0;            // t % 3
  for (int t = 0; t < T - 1; ++t) {
    // wait for stage t (own wave's oldest 4); leave stage t+1's 4 in flight
    asm volatile("s_waitcnt vmcnt(4)" ::: "memory");
    __builtin_amdgcn_sched_barrier(0);
    __builtin_amdgcn_s_barrier();  // cross-wave: all chunks of stage t in LDS
    __builtin_amdgcn_sched_barrier(0);
    if (t + 2 < T) {
      int b2 = (bt + 2 >= 3) ? bt - 1 : bt + 2;
      stage(lds[b2], t + 2);  // issue early: lands under compute
    }
    compute(lds[bt]);
    bt = (bt + 1 == 3) ? 0 : bt + 1;
  }
  // peeled final iteration: only stage T-1 outstanding
  asm volatile("s_waitcnt vmcnt(0)" ::: "memory");
  __builtin_amdgcn_sched_barrier(0);
  __builtin_amdgcn_s_barrier();
  __builtin_amdgcn_sched_barrier(0);
  compute(lds[bt]);

  const int r0 = (lane >> 4) * 4;
#pragma unroll
  for (int i = 0; i < 4; ++i)
#pragma unroll
    for (int j = 0; j < 4; ++j)
#pragma unroll
      for (int r = 0; r < 4; ++r) {
        int row = tm + wr * 64 + i * 16 + r0 + r;
        int col = tn + wc * 64 + j * 16 + lrow;
        float v = acc[i][j][r];
        if constexpr (sizeof(OutT) == 2)
          C[(size_t)row * N + col] = f2bf(v);
        else
          C[(size_t)row * N + col] = v;
      }
}

// ---------------------------------------------------------------------------
// GEMM 64x128 tile (output projection). B (Wo) is staging-tiled; A (attn
// output) stays row-major/strided this round to bound the blast radius.
// ---------------------------------------------------------------------------
__global__ __launch_bounds__(256) void gemm64(const unsigned short* __restrict__ A,
                                              const unsigned short* __restrict__ Bm,
                                              float* __restrict__ C, int N, int K) {
  __shared__ unsigned short lds[3][12 * 512];  // A: chunks 0-3, B: 4-11
  const int tid = threadIdx.x;
  const int lane = tid & 63;
  const int w = tid >> 6;
  const int wr = w >> 1, wc = w & 1;

  const int lid = blockIdx.y * gridDim.x + blockIdx.x;
  const int xcd = lid & 7;
  const int wgid = xcd * 64 + (lid >> 3);  // 0..511, contiguous per XCD
  const int s = wgid >> 5, w5 = wgid & 31; // supertile 0..15, within 0..31
  const int mt = (s & 3) * 16 + (w5 & 15); // 0..63
  const int nt = (s >> 2) * 2 + (w5 >> 4); // 0..7
  const int tm = mt * 64, tn = nt * 128;
  const int lrow = lane & 15;
  const int lk = (lane >> 4) * 8;

  floatx4 acc[2][4];
#pragma unroll
  for (int i = 0; i < 2; ++i)
#pragma unroll
    for (int j = 0; j < 4; ++j) acc[i][j] = floatx4{0.f, 0.f, 0.f, 0.f};

  auto stage = [&](unsigned short* buf, int t) {
#pragma unroll
    for (int c = w * 3; c < w * 3 + 3; ++c) {
      const unsigned short* g;
      if (c < 4) {
        g = A + (size_t)(tm + c * 16 + lrow) * K + (t * 32 + lk);
      } else {
        g = Bm + ((size_t)((nt * 32 + t) * 8 + (c - 4)) << 9) + lane * 8;
      }
      __builtin_amdgcn_global_load_lds((const AS1 uint32_t*)g,
                                       (AS3 uint32_t*)(buf + c * 512), 16, 0, 0);
    }
  };

  auto compute = [&](const unsigned short* L) {
    short8 af[2], bf[4];
#pragma unroll
    for (int i = 0; i < 2; ++i)
      af[i] = *(const short8*)&L[(wr * 2 + i) * 512 + lane * 8];
#pragma unroll
    for (int j = 0; j < 4; ++j)
      bf[j] = *(const short8*)&L[(4 + wc * 4 + j) * 512 + lane * 8];
#pragma unroll
    for (int i = 0; i < 2; ++i)
#pragma unroll
      for (int j = 0; j < 4; ++j) acc[i][j] = mfma16(af[i], bf[j], acc[i][j]);
  };

  stage(lds[0], 0);
  stage(lds[1], 1);

  const int T = K >> 5;  // 32
  int bt = 0;
  for (int t = 0; t < T - 1; ++t) {
    asm volatile("s_waitcnt vmcnt(3)" ::: "memory");
    __builtin_amdgcn_sched_barrier(0);
    __builtin_amdgcn_s_barrier();
    __builtin_amdgcn_sched_barrier(0);
    if (t + 2 < T) {
      int b2 = (bt + 2 >= 3) ? bt - 1 : bt + 2;
      stage(lds[b2], t + 2);
    }
    compute(lds[bt]);
    bt = (bt + 1 == 3) ? 0 : bt + 1;
  }
  asm volatile("s_waitcnt vmcnt(0)" ::: "memory");
  __builtin_amdgcn_sched_barrier(0);
  __builtin_amdgcn_s_barrier();
  __builtin_amdgcn_sched_barrier(0);
  compute(lds[bt]);

  const int r0 = (lane >> 4) * 4;
#pragma unroll
  for (int i = 0; i < 2; ++i)
#pragma unroll
    for (int j = 0; j < 4; ++j)
#pragma unroll
      for (int r = 0; r < 4; ++r) {
        int row = tm + (wr * 2 + i) * 16 + r0 + r;
        int col = tn + (wc * 4 + j) * 16 + lrow;
        C[(size_t)row * N + col] = acc[i][j][r];
      }
}

// ---------------------------------------------------------------------------
// Flash attention, S^T orientation, 128 q/WG, 128-key blocks + 16-key sink.
// (unchanged from the proven baseline)
// ---------------------------------------------------------------------------
__global__ __launch_bounds__(256) void attn_kernel(const unsigned short* __restrict__ qkv,
                                                   unsigned short* __restrict__ aout) {
  __shared__ unsigned short Klds[2][16 * 512];  // 2 x 16KB A-frag chunks
  __shared__ unsigned short VT[64 * 136];       // V^T [d][key], stride 136
  __shared__ unsigned short PT[4][16 * 136];    // per-wave P^T [q][key]

  const int tid = threadIdx.x;
  const int lane = tid & 63;
  const int w = tid >> 6;
  const int lrow = lane & 15;
  const int lkg = lane >> 4;

  const int i = blockIdx.x;
  const int half = i >> 8;
  const int j = (i >> 3) & 31;
  const int h = 2 * (i & 7) + half;
  const int qb = half ? (31 - j) : j;
  const int q0 = qb * 128;

  short8 qf[2][2];
#pragma unroll
  for (int qt = 0; qt < 2; ++qt)
#pragma unroll
    for (int ks = 0; ks < 2; ++ks)
      qf[qt][ks] = *(const short8*)&qkv[(size_t)(q0 + qt * 64 + w * 16 + lrow) * 3072 +
                                        h * 64 + ks * 32 + lkg * 8];

  float m_i[2], l_i[2];
  floatx4 o[4][2];
#pragma unroll
  for (int qt = 0; qt < 2; ++qt) {
    m_i[qt] = -1e30f;
    l_i[qt] = 0.f;
#pragma unroll
    for (int nt = 0; nt < 4; ++nt) o[nt][qt] = floatx4{0.f, 0.f, 0.f, 0.f};
  }

  const float scale2 = 0.125f * 1.44269504088896f;  // 1/sqrt(64) * log2(e)

  // ---- prologue: stage sink K/V; prefetch window block 0 ----
  if (w < 2) {  // sink K chunks 0,1 into Klds[0]
    const unsigned short* g = &qkv[(size_t)lrow * 3072 + 1024 + h * 64 + w * 32 + lkg * 8];
    __builtin_amdgcn_global_load_lds((const AS1 uint32_t*)g,
                                     (AS3 uint32_t*)(&Klds[0][w * 512]), 16, 0, 0);
  }
  {  // sink V^T keys 0..31 (PV spans 0..31; P=0 for 16..31)
    if (lane < 16) {
      const unsigned short* g0 = &qkv[(size_t)(2 * lane) * 3072 + 2048 + h * 64 + w * 16];
      ushort8 a0 = *(const ushort8*)g0;
      ushort8 a1 = *(const ushort8*)(g0 + 8);
      ushort8 b0 = *(const ushort8*)(g0 + 3072);
      ushort8 b1 = *(const ushort8*)(g0 + 3080);
      uint32_t* vt = (uint32_t*)VT;
#pragma unroll
      for (int dd = 0; dd < 8; ++dd) {
        vt[(w * 16 + dd) * 68 + lane] = (uint32_t)a0[dd] | ((uint32_t)b0[dd] << 16);
        vt[(w * 16 + 8 + dd) * 68 + lane] = (uint32_t)a1[dd] | ((uint32_t)b1[dd] << 16);
      }
    }
  }
  const int kb0 = (q0 - 511 < 16) ? 16 : (q0 - 511);
  // prefetch window block 0: K -> Klds[1], V -> registers
#pragma unroll
  for (int c = 0; c < 4; ++c) {
    int ch = w * 4 + c;
    int kt = ch >> 1, ks = ch & 1;
    const unsigned short* g =
        &qkv[(size_t)(kb0 + kt * 16 + lrow) * 3072 + 1024 + h * 64 + ks * 32 + lkg * 8];
    __builtin_amdgcn_global_load_lds((const AS1 uint32_t*)g,
                                     (AS3 uint32_t*)(&Klds[1][ch * 512]), 16, 0, 0);
  }
  ushort8 va0, va1, vb0, vb1;
  {
    const unsigned short* g0 = &qkv[(size_t)(kb0 + 2 * lane) * 3072 + 2048 + h * 64 + w * 16];
    va0 = *(const ushort8*)g0;
    va1 = *(const ushort8*)(g0 + 8);
    vb0 = *(const ushort8*)(g0 + 3072);
    vb1 = *(const ushort8*)(g0 + 3080);
  }
  __syncthreads();

  // ---- sink compute (keys 0..15; PV over 0..31 with P=0 padding) ----
#pragma unroll
  for (int qt = 0; qt < 2; ++qt) {
    const int qq = q0 + qt * 64 + w * 16 + lrow;
    floatx4 s0 = floatx4{0.f, 0.f, 0.f, 0.f};
#pragma unroll
    for (int ks = 0; ks < 2; ++ks) {
      short8 kf = *(const short8*)&Klds[0][ks * 512 + lane * 8];
      s0 = mfma16(kf, qf[qt][ks], s0);
    }
    float mx = -1e30f;
    float sv[4];
#pragma unroll
    for (int r = 0; r < 4; ++r) {
      int key = lkg * 4 + r;
      bool vis = (key <= qq) && ((key < 4) || (key >= qq - 511));
      sv[r] = vis ? s0[r] * scale2 : -1e30f;
      mx = fmaxf(mx, sv[r]);
    }
    mx = fmaxf(mx, __shfl_xor(mx, 16));
    mx = fmaxf(mx, __shfl_xor(mx, 32));
    m_i[qt] = mx;  // key 0 always visible -> finite
    float p0 = exp2f(sv[0] - mx), p1 = exp2f(sv[1] - mx);
    float p2 = exp2f(sv[2] - mx), p3 = exp2f(sv[3] - mx);
    float ps = (p0 + p1) + (p2 + p3);
    *(uint2*)&PT[w][lrow * 136 + lkg * 4] = uint2{cvt_pk_bf16(p0, p1), cvt_pk_bf16(p2, p3)};
    *(uint2*)&PT[w][lrow * 136 + 16 + lkg * 4] = uint2{0u, 0u};  // keys 16..31 = 0
    ps += __shfl_xor(ps, 16);
    ps += __shfl_xor(ps, 32);
    l_i[qt] = ps;
    short8 pf = *(const short8*)&PT[w][lrow * 136 + lkg * 8];
#pragma unroll
    for (int nt = 0; nt < 4; ++nt) {
      short8 vf = *(const short8*)&VT[(nt * 16 + lrow) * 136 + lkg * 8];
      o[nt][qt] = mfma16(vf, pf, o[nt][qt]);
    }
  }

  // ---- window blocks of 128 keys (pipelined) ----
  int nbuf = 1;
  for (int kb = kb0; kb < q0 + 128; kb += 128) {
    const bool hasnext = (kb + 128 < q0 + 128);
    __syncthreads();  // prev readers of VT done; this block's K/V prefetch drained (landed)
    {  // write V^T for this block from prefetched registers
      uint32_t* vt = (uint32_t*)VT;
#pragma unroll
      for (int dd = 0; dd < 8; ++dd) {
        vt[(w * 16 + dd) * 68 + lane] = (uint32_t)va0[dd] | ((uint32_t)vb0[dd] << 16);
        vt[(w * 16 + 8 + dd) * 68 + lane] = (uint32_t)va1[dd] | ((uint32_t)vb1[dd] << 16);
      }
    }
    __syncthreads();  // VT visible

    // issue prefetches for block n+1 (after the barrier so the drain above
    // never waits on them; they land during this block's compute)
    if (hasnext) {
      const int kn = kb + 128;
#pragma unroll
      for (int c = 0; c < 4; ++c) {
        int ch = w * 4 + c;
        int kt = ch >> 1, ks = ch & 1;
        const unsigned short* g =
            &qkv[(size_t)(kn + kt * 16 + lrow) * 3072 + 1024 + h * 64 + ks * 32 + lkg * 8];
        __builtin_amdgcn_global_load_lds((const AS1 uint32_t*)g,
                                         (AS3 uint32_t*)(&Klds[1 - nbuf][ch * 512]), 16, 0, 0);
      }
      const unsigned short* g0 = &qkv[(size_t)(kn + 2 * lane) * 3072 + 2048 + h * 64 + w * 16];
      va0 = *(const ushort8*)g0;
      va1 = *(const ushort8*)(g0 + 8);
      vb0 = *(const ushort8*)(g0 + 3072);
      vb1 = *(const ushort8*)(g0 + 3080);
    }

#pragma unroll
    for (int qt = 0; qt < 2; ++qt) {
      const int qaT = q0 + qt * 64 + w * 16;  // wave-uniform
      const int qq = qaT + lrow;
      floatx4 s[8];
#pragma unroll
      for (int ct = 0; ct < 8; ++ct) {
        s[ct] = floatx4{0.f, 0.f, 0.f, 0.f};
#pragma unroll
        for (int ks = 0; ks < 2; ++ks) {
          short8 kf = *(const short8*)&Klds[nbuf][(ct * 2 + ks) * 512 + lane * 8];
          s[ct] = mfma16(kf, qf[qt][ks], s[ct]);
        }
      }
      const bool full = (kb + 127 <= qaT) && (kb >= qaT + 15 - 511);
      float mx = -1e30f;
#pragma unroll
      for (int ct = 0; ct < 8; ++ct)
#pragma unroll
        for (int r = 0; r < 4; ++r) {
          float val = s[ct][r] * scale2;
          if (!full) {
            int key = kb + ct * 16 + lkg * 4 + r;
            bool vis = (key <= qq) && (key >= qq - 511);
            val = vis ? val : -1e30f;
          }
          s[ct][r] = val;
          mx = fmaxf(mx, val);
        }
      mx = fmaxf(mx, __shfl_xor(mx, 16));
      mx = fmaxf(mx, __shfl_xor(mx, 32));
      float nm = fmaxf(m_i[qt], mx);
      float alpha = exp2f(m_i[qt] - nm);
      m_i[qt] = nm;

      float ps = 0.f;
#pragma unroll
      for (int ct = 0; ct < 8; ++ct) {
        float p0 = exp2f(s[ct][0] - nm), p1 = exp2f(s[ct][1] - nm);
        float p2 = exp2f(s[ct][2] - nm), p3 = exp2f(s[ct][3] - nm);
        ps += (p0 + p1) + (p2 + p3);
        *(uint2*)&PT[w][lrow * 136 + ct * 16 + lkg * 4] =
            uint2{cvt_pk_bf16(p0, p1), cvt_pk_bf16(p2, p3)};
      }
      ps += __shfl_xor(ps, 16);
      ps += __shfl_xor(ps, 32);
      l_i[qt] = l_i[qt] * alpha + ps;

#pragma unroll
      for (int nt = 0; nt < 4; ++nt)
#pragma unroll
        for (int r = 0; r < 4; ++r) o[nt][qt][r] *= alpha;

#pragma unroll
      for (int kk = 0; kk < 4; ++kk) {
        short8 pf = *(const short8*)&PT[w][lrow * 136 + kk * 32 + lkg * 8];
#pragma unroll
        for (int nt = 0; nt < 4; ++nt) {
          short8 vf = *(const short8*)&VT[(nt * 16 + lrow) * 136 + kk * 32 + lkg * 8];
          o[nt][qt] = mfma16(vf, pf, o[nt][qt]);
        }
      }
    }
    nbuf ^= 1;
  }

#pragma unroll
  for (int qt = 0; qt < 2; ++qt) {
    const int qq = q0 + qt * 64 + w * 16 + lrow;
    const float inv = 1.0f / l_i[qt];
#pragma unroll
    for (int nt = 0; nt < 4; ++nt) {
      floatx4 ov = o[nt][qt];
      uint32_t lo = cvt_pk_bf16(ov[0] * inv, ov[1] * inv);
      uint32_t hi = cvt_pk_bf16(ov[2] * inv, ov[3] * inv);
      *(uint2*)&aout[(size_t)qq * 1024 + h * 64 + nt * 16 + lkg * 4] = uint2{lo, hi};
    }
  }
}

// ---------------------------------------------------------------------------
extern "C" void kernel_launch(void* const* d_in, const int* in_sizes, int n_in,
                              void* d_out, int out_size, void* d_ws, size_t ws_size,
                              hipStream_t stream) {
  const float* x = (const float*)d_in[0];
  const float* wq = (const float*)d_in[1];
  const float* wk = (const float*)d_in[2];
  const float* wv = (const float*)d_in[3];
  const float* wo = (const float*)d_in[4];

  char* ws = (char*)d_ws;
  unsigned short* Xb = (unsigned short*)(ws);                 // 8 MB (tiled)
  unsigned short* Wqkv = (unsigned short*)(ws + (8u << 20));  // 6 MB (tiled)
  unsigned short* Wob = (unsigned short*)(ws + (14u << 20));  // 2 MB (tiled)
  unsigned short* QKV = (unsigned short*)(ws + (16u << 20));  // 24 MB
  unsigned short* AO = (unsigned short*)(ws + (40u << 20));   // 8 MB

  convert_pack<<<4096, 256, 0, stream>>>((const float4*)x, (const float4*)wq,
                                         (const float4*)wk, (const float4*)wv,
                                         (const float4*)wo, Xb, Wqkv, Wob);
  gemm_bt<unsigned short><<<dim3(32, 24), 256, 0, stream>>>(Xb, Wqkv, QKV, 3072, 1024);
  attn_kernel<<<512, 256, 0, stream>>>(QKV, AO);
  gemm64<<<dim3(64, 8), 256, 0, stream>>>(AO, Wob, (float*)d_out, 1024, 1024);
}

// Round 5
// 159.154 us; speedup vs baseline: 1.2746x; 1.0797x over previous
//
#include <hip/hip_runtime.h>
#include <stdint.h>

#define AS1 __attribute__((address_space(1)))
#define AS3 __attribute__((address_space(3)))

typedef short short8 __attribute__((ext_vector_type(8)));
typedef unsigned short ushort8 __attribute__((ext_vector_type(8)));
typedef __bf16 bf16x8 __attribute__((ext_vector_type(8)));
typedef float floatx4 __attribute__((ext_vector_type(4)));

__device__ __forceinline__ floatx4 mfma16(short8 a, short8 b, floatx4 c) {
  return __builtin_amdgcn_mfma_f32_16x16x32_bf16(
      __builtin_bit_cast(bf16x8, a), __builtin_bit_cast(bf16x8, b), c, 0, 0, 0);
}

__device__ __forceinline__ unsigned short f2bf(float f) {
  uint32_t u = __builtin_bit_cast(uint32_t, f);
  u = (u + 0x7FFFu + ((u >> 16) & 1u)) >> 16;
  return (unsigned short)u;
}

// packed f32x2 -> bf16x2, 1 VALU instr for 2 values
__device__ __forceinline__ uint32_t cvt_pk_bf16(float a, float b) {
  uint32_t d;
  asm("v_cvt_pk_bf16_f32 %0, %1, %2" : "=v"(d) : "v"(a), "v"(b));
  return d;
}

// ---------------------------------------------------------------------------
// Staging-tiled layout (validated on HW in round 4): matrix stored as 1-KB
// blocks, block blk = ((row/128)*32 + col/32)*8 + (row/16)%8, content
// lane-linear: elem (lane*8+e) = M[16rowgrp + lane%16][colgrp*8(lane/16)+e].
// Every gemm global_load_lds chunk = one contiguous 1-KB lane-linear read.
// ---------------------------------------------------------------------------
__device__ __forceinline__ size_t tiled_off(int row, int col) {
  int rt = row >> 7, c8 = (row >> 4) & 7, rr = row & 15;
  int t = col >> 5, lh = (col >> 3) & 3, e = col & 7;
  return ((size_t)((rt * 32 + t) * 8 + c8) << 9) + (lh * 16 + rr) * 8 + e;
}

// ---------------------------------------------------------------------------
// Convert/pack v3: one WAVE per 1-KB output block. Reads: per 16-row group,
// 4 lanes cover a full 128-B line (no sector waste). Writes: wave-contiguous
// 1 KB (fixes round-4's scattered 16B@256B-stride writes).
// Blocks: Xb 8192 | Wqkv 6144 | Wob 2048 = 16384 waves = 4096 WGs.
// ---------------------------------------------------------------------------
__global__ __launch_bounds__(256) void convert_pack(
    const float* __restrict__ x, const float* __restrict__ wq,
    const float* __restrict__ wk, const float* __restrict__ wv,
    const float* __restrict__ wo, unsigned short* __restrict__ xb,
    unsigned short* __restrict__ wqkvb, unsigned short* __restrict__ wob) {
  const int lane = threadIdx.x & 63;
  const int wid = threadIdx.x >> 6;
  const int b = blockIdx.x * 4 + wid;  // 0..16383
  const int lrow = lane & 15, lkg = lane >> 4;
  const float* src;
  unsigned short* dst;
  if (b < 8192) {  // x: 4096x1024
    int rt = b >> 8, wi = b & 255, t = wi >> 3, c8 = wi & 7;
    int row = rt * 128 + c8 * 16 + lrow;
    src = x + (size_t)row * 1024 + t * 32 + lkg * 8;
    dst = xb + ((size_t)b << 9) + lane * 8;
  } else if (b < 14336) {  // Wq|Wk|Wv -> Wqkv rows 0..3071
    int jb = b - 8192;
    int rt = jb >> 8, wi = jb & 255, t = wi >> 3, c8 = wi & 7;
    int row = rt * 128 + c8 * 16 + lrow;  // 0..3071
    int r = row >> 10, srow = row & 1023;
    const float* m = (r == 0) ? wq : (r == 1) ? wk : wv;
    src = m + (size_t)srow * 1024 + t * 32 + lkg * 8;
    dst = wqkvb + ((size_t)jb << 9) + lane * 8;
  } else {  // Wo: 1024x1024
    int jb = b - 14336;
    int rt = jb >> 8, wi = jb & 255, t = wi >> 3, c8 = wi & 7;
    int row = rt * 128 + c8 * 16 + lrow;
    src = wo + (size_t)row * 1024 + t * 32 + lkg * 8;
    dst = wob + ((size_t)jb << 9) + lane * 8;
  }
  float4 a = *(const float4*)src;
  float4 c = *(const float4*)(src + 4);
  ushort8 o;
  o[0] = f2bf(a.x); o[1] = f2bf(a.y); o[2] = f2bf(a.z); o[3] = f2bf(a.w);
  o[4] = f2bf(c.x); o[5] = f2bf(c.y); o[6] = f2bf(c.z); o[7] = f2bf(c.w);
  *(ushort8*)dst = o;
}

// ---------------------------------------------------------------------------
// GEMM 128x128 tile (QKV projection): C[M][N] = A[M][K] @ B[N][K]^T.
// A and B staging-tiled: each chunk load is a contiguous 1-KB lane-linear
// read. Pipeline: 3 x 16KB buffers, depth-2 prefetch, counted vmcnt(4),
// raw s_barrier (round-3 structure). XCD-compact supertile swizzle.
// ---------------------------------------------------------------------------
template <typename OutT>
__global__ __launch_bounds__(256) void gemm_bt(const unsigned short* __restrict__ A,
                                               const unsigned short* __restrict__ Bm,
                                               OutT* __restrict__ C, int N, int K) {
  __shared__ unsigned short lds[3][16 * 512];  // 3 x 16 KB (BK=32)
  const int tid = threadIdx.x;
  const int lane = tid & 63;
  const int w = tid >> 6;
  const int wr = w >> 1, wc = w & 1;

  // XCD-compact supertile swizzle for grid (32,24)=768 (bijective).
  const int lid = blockIdx.y * gridDim.x + blockIdx.x;
  const int xcd = lid & 7;
  const int wgid = xcd * 96 + (lid >> 3);  // 0..767, contiguous per XCD
  const int s = wgid >> 5, w5 = wgid & 31; // supertile 0..23, within 0..31
  const int mt = (s & 3) * 8 + (w5 & 7);   // 0..31
  const int nt = (s >> 2) * 4 + (w5 >> 3); // 0..23
  const int tm = mt * 128, tn = nt * 128;
  const int lrow = lane & 15;

  floatx4 acc[4][4];
#pragma unroll
  for (int i = 0; i < 4; ++i)
#pragma unroll
    for (int j = 0; j < 4; ++j) acc[i][j] = floatx4{0.f, 0.f, 0.f, 0.f};

  // Tiled staging: chunk c of K-step t is contiguous at blk*1KB.
  auto stage = [&](unsigned short* buf, int t) {
#pragma unroll
    for (int c = w * 4; c < w * 4 + 4; ++c) {
      const unsigned short* g;
      if (c < 8)
        g = A + ((size_t)((mt * 32 + t) * 8 + c) << 9) + lane * 8;
      else
        g = Bm + ((size_t)((nt * 32 + t) * 8 + (c - 8)) << 9) + lane * 8;
      __builtin_amdgcn_global_load_lds((const AS1 uint32_t*)g,
                                       (AS3 uint32_t*)(buf + c * 512), 16, 0, 0);
    }
  };

  auto compute = [&](const unsigned short* L) {
    short8 af[4], bf[4];
#pragma unroll
    for (int i = 0; i < 4; ++i)
      af[i] = *(const short8*)&L[(wr * 4 + i) * 512 + lane * 8];
#pragma unroll
    for (int j = 0; j < 4; ++j)
      bf[j] = *(const short8*)&L[(8 + wc * 4 + j) * 512 + lane * 8];
#pragma unroll
    for (int i = 0; i < 4; ++i)
#pragma unroll
      for (int j = 0; j < 4; ++j) acc[i][j] = mfma16(af[i], bf[j], acc[i][j]);
  };

  stage(lds[0], 0);
  stage(lds[1], 1);

  const int T = K >> 5;  // 32
  int bt = 0;            // t % 3
  for (int t = 0; t < T - 1; ++t) {
    // wait for stage t (own wave's oldest 4); leave stage t+1's 4 in flight
    asm volatile("s_waitcnt vmcnt(4)" ::: "memory");
    __builtin_amdgcn_sched_barrier(0);
    __builtin_amdgcn_s_barrier();  // cross-wave: all chunks of stage t in LDS
    __builtin_amdgcn_sched_barrier(0);
    if (t + 2 < T) {
      int b2 = (bt + 2 >= 3) ? bt - 1 : bt + 2;
      stage(lds[b2], t + 2);  // issue early: lands under compute
    }
    compute(lds[bt]);
    bt = (bt + 1 == 3) ? 0 : bt + 1;
  }
  // peeled final iteration: only stage T-1 outstanding
  asm volatile("s_waitcnt vmcnt(0)" ::: "memory");
  __builtin_amdgcn_sched_barrier(0);
  __builtin_amdgcn_s_barrier();
  __builtin_amdgcn_sched_barrier(0);
  compute(lds[bt]);

  const int r0 = (lane >> 4) * 4;
#pragma unroll
  for (int i = 0; i < 4; ++i)
#pragma unroll
    for (int j = 0; j < 4; ++j)
#pragma unroll
      for (int r = 0; r < 4; ++r) {
        int row = tm + wr * 64 + i * 16 + r0 + r;
        int col = tn + wc * 64 + j * 16 + lrow;
        float v = acc[i][j][r];
        if constexpr (sizeof(OutT) == 2)
          C[(size_t)row * N + col] = f2bf(v);
        else
          C[(size_t)row * N + col] = v;
      }
}

// ---------------------------------------------------------------------------
// GEMM 64x128 tile (output projection). BOTH sides now staging-tiled:
// B (Wo) from convert_pack, A (AO) written tiled by attn_kernel. All 12
// chunks per K-step are contiguous 1-KB lane-linear reads.
// ---------------------------------------------------------------------------
__global__ __launch_bounds__(256) void gemm64(const unsigned short* __restrict__ A,
                                              const unsigned short* __restrict__ Bm,
                                              float* __restrict__ C, int N, int K) {
  __shared__ unsigned short lds[3][12 * 512];  // A: chunks 0-3, B: 4-11
  const int tid = threadIdx.x;
  const int lane = tid & 63;
  const int w = tid >> 6;
  const int wr = w >> 1, wc = w & 1;

  const int lid = blockIdx.y * gridDim.x + blockIdx.x;
  const int xcd = lid & 7;
  const int wgid = xcd * 64 + (lid >> 3);  // 0..511, contiguous per XCD
  const int s = wgid >> 5, w5 = wgid & 31; // supertile 0..15, within 0..31
  const int mt = (s & 3) * 16 + (w5 & 15); // 0..63
  const int nt = (s >> 2) * 2 + (w5 >> 4); // 0..7
  const int tm = mt * 64, tn = nt * 128;
  const int lrow = lane & 15;

  floatx4 acc[2][4];
#pragma unroll
  for (int i = 0; i < 2; ++i)
#pragma unroll
    for (int j = 0; j < 4; ++j) acc[i][j] = floatx4{0.f, 0.f, 0.f, 0.f};

  // A tile rows tm..tm+63: 128-row tile rt = mt>>1, chunks (mt&1)*4 + c.
  auto stage = [&](unsigned short* buf, int t) {
#pragma unroll
    for (int c = w * 3; c < w * 3 + 3; ++c) {
      const unsigned short* g;
      if (c < 4)
        g = A + ((size_t)(((mt >> 1) * 32 + t) * 8 + ((mt & 1) * 4 + c)) << 9) + lane * 8;
      else
        g = Bm + ((size_t)((nt * 32 + t) * 8 + (c - 4)) << 9) + lane * 8;
      __builtin_amdgcn_global_load_lds((const AS1 uint32_t*)g,
                                       (AS3 uint32_t*)(buf + c * 512), 16, 0, 0);
    }
  };

  auto compute = [&](const unsigned short* L) {
    short8 af[2], bf[4];
#pragma unroll
    for (int i = 0; i < 2; ++i)
      af[i] = *(const short8*)&L[(wr * 2 + i) * 512 + lane * 8];
#pragma unroll
    for (int j = 0; j < 4; ++j)
      bf[j] = *(const short8*)&L[(4 + wc * 4 + j) * 512 + lane * 8];
#pragma unroll
    for (int i = 0; i < 2; ++i)
#pragma unroll
      for (int j = 0; j < 4; ++j) acc[i][j] = mfma16(af[i], bf[j], acc[i][j]);
  };

  stage(lds[0], 0);
  stage(lds[1], 1);

  const int T = K >> 5;  // 32
  int bt = 0;
  for (int t = 0; t < T - 1; ++t) {
    asm volatile("s_waitcnt vmcnt(3)" ::: "memory");
    __builtin_amdgcn_sched_barrier(0);
    __builtin_amdgcn_s_barrier();
    __builtin_amdgcn_sched_barrier(0);
    if (t + 2 < T) {
      int b2 = (bt + 2 >= 3) ? bt - 1 : bt + 2;
      stage(lds[b2], t + 2);
    }
    compute(lds[bt]);
    bt = (bt + 1 == 3) ? 0 : bt + 1;
  }
  asm volatile("s_waitcnt vmcnt(0)" ::: "memory");
  __builtin_amdgcn_sched_barrier(0);
  __builtin_amdgcn_s_barrier();
  __builtin_amdgcn_sched_barrier(0);
  compute(lds[bt]);

  const int r0 = (lane >> 4) * 4;
#pragma unroll
  for (int i = 0; i < 2; ++i)
#pragma unroll
    for (int j = 0; j < 4; ++j)
#pragma unroll
      for (int r = 0; r < 4; ++r) {
        int row = tm + (wr * 2 + i) * 16 + r0 + r;
        int col = tn + (wc * 4 + j) * 16 + lrow;
        C[(size_t)row * N + col] = acc[i][j][r];
      }
}

// ---------------------------------------------------------------------------
// Flash attention, S^T orientation, 128 q/WG, 128-key blocks + 16-key sink.
// Compute unchanged; epilogue now writes AO in staging-tiled layout for
// gemm64 (wave store pattern stays 512-B contiguous per nt).
// ---------------------------------------------------------------------------
__global__ __launch_bounds__(256) void attn_kernel(const unsigned short* __restrict__ qkv,
                                                   unsigned short* __restrict__ aout) {
  __shared__ unsigned short Klds[2][16 * 512];  // 2 x 16KB A-frag chunks
  __shared__ unsigned short VT[64 * 136];       // V^T [d][key], stride 136
  __shared__ unsigned short PT[4][16 * 136];    // per-wave P^T [q][key]

  const int tid = threadIdx.x;
  const int lane = tid & 63;
  const int w = tid >> 6;
  const int lrow = lane & 15;
  const int lkg = lane >> 4;

  const int i = blockIdx.x;
  const int half = i >> 8;
  const int j = (i >> 3) & 31;
  const int h = 2 * (i & 7) + half;
  const int qb = half ? (31 - j) : j;
  const int q0 = qb * 128;

  short8 qf[2][2];
#pragma unroll
  for (int qt = 0; qt < 2; ++qt)
#pragma unroll
    for (int ks = 0; ks < 2; ++ks)
      qf[qt][ks] = *(const short8*)&qkv[(size_t)(q0 + qt * 64 + w * 16 + lrow) * 3072 +
                                        h * 64 + ks * 32 + lkg * 8];

  float m_i[2], l_i[2];
  floatx4 o[4][2];
#pragma unroll
  for (int qt = 0; qt < 2; ++qt) {
    m_i[qt] = -1e30f;
    l_i[qt] = 0.f;
#pragma unroll
    for (int nt = 0; nt < 4; ++nt) o[nt][qt] = floatx4{0.f, 0.f, 0.f, 0.f};
  }

  const float scale2 = 0.125f * 1.44269504088896f;  // 1/sqrt(64) * log2(e)

  // ---- prologue: stage sink K/V; prefetch window block 0 ----
  if (w < 2) {  // sink K chunks 0,1 into Klds[0]
    const unsigned short* g = &qkv[(size_t)lrow * 3072 + 1024 + h * 64 + w * 32 + lkg * 8];
    __builtin_amdgcn_global_load_lds((const AS1 uint32_t*)g,
                                     (AS3 uint32_t*)(&Klds[0][w * 512]), 16, 0, 0);
  }
  {  // sink V^T keys 0..31 (PV spans 0..31; P=0 for 16..31)
    if (lane < 16) {
      const unsigned short* g0 = &qkv[(size_t)(2 * lane) * 3072 + 2048 + h * 64 + w * 16];
      ushort8 a0 = *(const ushort8*)g0;
      ushort8 a1 = *(const ushort8*)(g0 + 8);
      ushort8 b0 = *(const ushort8*)(g0 + 3072);
      ushort8 b1 = *(const ushort8*)(g0 + 3080);
      uint32_t* vt = (uint32_t*)VT;
#pragma unroll
      for (int dd = 0; dd < 8; ++dd) {
        vt[(w * 16 + dd) * 68 + lane] = (uint32_t)a0[dd] | ((uint32_t)b0[dd] << 16);
        vt[(w * 16 + 8 + dd) * 68 + lane] = (uint32_t)a1[dd] | ((uint32_t)b1[dd] << 16);
      }
    }
  }
  const int kb0 = (q0 - 511 < 16) ? 16 : (q0 - 511);
  // prefetch window block 0: K -> Klds[1], V -> registers
#pragma unroll
  for (int c = 0; c < 4; ++c) {
    int ch = w * 4 + c;
    int kt = ch >> 1, ks = ch & 1;
    const unsigned short* g =
        &qkv[(size_t)(kb0 + kt * 16 + lrow) * 3072 + 1024 + h * 64 + ks * 32 + lkg * 8];
    __builtin_amdgcn_global_load_lds((const AS1 uint32_t*)g,
                                     (AS3 uint32_t*)(&Klds[1][ch * 512]), 16, 0, 0);
  }
  ushort8 va0, va1, vb0, vb1;
  {
    const unsigned short* g0 = &qkv[(size_t)(kb0 + 2 * lane) * 3072 + 2048 + h * 64 + w * 16];
    va0 = *(const ushort8*)g0;
    va1 = *(const ushort8*)(g0 + 8);
    vb0 = *(const ushort8*)(g0 + 3072);
    vb1 = *(const ushort8*)(g0 + 3080);
  }
  __syncthreads();

  // ---- sink compute (keys 0..15; PV over 0..31 with P=0 padding) ----
#pragma unroll
  for (int qt = 0; qt < 2; ++qt) {
    const int qq = q0 + qt * 64 + w * 16 + lrow;
    floatx4 s0 = floatx4{0.f, 0.f, 0.f, 0.f};
#pragma unroll
    for (int ks = 0; ks < 2; ++ks) {
      short8 kf = *(const short8*)&Klds[0][ks * 512 + lane * 8];
      s0 = mfma16(kf, qf[qt][ks], s0);
    }
    float mx = -1e30f;
    float sv[4];
#pragma unroll
    for (int r = 0; r < 4; ++r) {
      int key = lkg * 4 + r;
      bool vis = (key <= qq) && ((key < 4) || (key >= qq - 511));
      sv[r] = vis ? s0[r] * scale2 : -1e30f;
      mx = fmaxf(mx, sv[r]);
    }
    mx = fmaxf(mx, __shfl_xor(mx, 16));
    mx = fmaxf(mx, __shfl_xor(mx, 32));
    m_i[qt] = mx;  // key 0 always visible -> finite
    float p0 = exp2f(sv[0] - mx), p1 = exp2f(sv[1] - mx);
    float p2 = exp2f(sv[2] - mx), p3 = exp2f(sv[3] - mx);
    float ps = (p0 + p1) + (p2 + p3);
    *(uint2*)&PT[w][lrow * 136 + lkg * 4] = uint2{cvt_pk_bf16(p0, p1), cvt_pk_bf16(p2, p3)};
    *(uint2*)&PT[w][lrow * 136 + 16 + lkg * 4] = uint2{0u, 0u};  // keys 16..31 = 0
    ps += __shfl_xor(ps, 16);
    ps += __shfl_xor(ps, 32);
    l_i[qt] = ps;
    short8 pf = *(const short8*)&PT[w][lrow * 136 + lkg * 8];
#pragma unroll
    for (int nt = 0; nt < 4; ++nt) {
      short8 vf = *(const short8*)&VT[(nt * 16 + lrow) * 136 + lkg * 8];
      o[nt][qt] = mfma16(vf, pf, o[nt][qt]);
    }
  }

  // ---- window blocks of 128 keys (pipelined) ----
  int nbuf = 1;
  for (int kb = kb0; kb < q0 + 128; kb += 128) {
    const bool hasnext = (kb + 128 < q0 + 128);
    __syncthreads();  // prev readers of VT done; this block's K/V prefetch drained (landed)
    {  // write V^T for this block from prefetched registers
      uint32_t* vt = (uint32_t*)VT;
#pragma unroll
      for (int dd = 0; dd < 8; ++dd) {
        vt[(w * 16 + dd) * 68 + lane] = (uint32_t)va0[dd] | ((uint32_t)vb0[dd] << 16);
        vt[(w * 16 + 8 + dd) * 68 + lane] = (uint32_t)va1[dd] | ((uint32_t)vb1[dd] << 16);
      }
    }
    __syncthreads();  // VT visible

    // issue prefetches for block n+1 (after the barrier so the drain above
    // never waits on them; they land during this block's compute)
    if (hasnext) {
      const int kn = kb + 128;
#pragma unroll
      for (int c = 0; c < 4; ++c) {
        int ch = w * 4 + c;
        int kt = ch >> 1, ks = ch & 1;
        const unsigned short* g =
            &qkv[(size_t)(kn + kt * 16 + lrow) * 3072 + 1024 + h * 64 + ks * 32 + lkg * 8];
        __builtin_amdgcn_global_load_lds((const AS1 uint32_t*)g,
                                         (AS3 uint32_t*)(&Klds[1 - nbuf][ch * 512]), 16, 0, 0);
      }
      const unsigned short* g0 = &qkv[(size_t)(kn + 2 * lane) * 3072 + 2048 + h * 64 + w * 16];
      va0 = *(const ushort8*)g0;
      va1 = *(const ushort8*)(g0 + 8);
      vb0 = *(const ushort8*)(g0 + 3072);
      vb1 = *(const ushort8*)(g0 + 3080);
    }

#pragma unroll
    for (int qt = 0; qt < 2; ++qt) {
      const int qaT = q0 + qt * 64 + w * 16;  // wave-uniform
      const int qq = qaT + lrow;
      floatx4 s[8];
#pragma unroll
      for (int ct = 0; ct < 8; ++ct) {
        s[ct] = floatx4{0.f, 0.f, 0.f, 0.f};
#pragma unroll
        for (int ks = 0; ks < 2; ++ks) {
          short8 kf = *(const short8*)&Klds[nbuf][(ct * 2 + ks) * 512 + lane * 8];
          s[ct] = mfma16(kf, qf[qt][ks], s[ct]);
        }
      }
      const bool full = (kb + 127 <= qaT) && (kb >= qaT + 15 - 511);
      float mx = -1e30f;
#pragma unroll
      for (int ct = 0; ct < 8; ++ct)
#pragma unroll
        for (int r = 0; r < 4; ++r) {
          float val = s[ct][r] * scale2;
          if (!full) {
            int key = kb + ct * 16 + lkg * 4 + r;
            bool vis = (key <= qq) && (key >= qq - 511);
            val = vis ? val : -1e30f;
          }
          s[ct][r] = val;
          mx = fmaxf(mx, val);
        }
      mx = fmaxf(mx, __shfl_xor(mx, 16));
      mx = fmaxf(mx, __shfl_xor(mx, 32));
      float nm = fmaxf(m_i[qt], mx);
      float alpha = exp2f(m_i[qt] - nm);
      m_i[qt] = nm;

      float ps = 0.f;
#pragma unroll
      for (int ct = 0; ct < 8; ++ct) {
        float p0 = exp2f(s[ct][0] - nm), p1 = exp2f(s[ct][1] - nm);
        float p2 = exp2f(s[ct][2] - nm), p3 = exp2f(s[ct][3] - nm);
        ps += (p0 + p1) + (p2 + p3);
        *(uint2*)&PT[w][lrow * 136 + ct * 16 + lkg * 4] =
            uint2{cvt_pk_bf16(p0, p1), cvt_pk_bf16(p2, p3)};
      }
      ps += __shfl_xor(ps, 16);
      ps += __shfl_xor(ps, 32);
      l_i[qt] = l_i[qt] * alpha + ps;

#pragma unroll
      for (int nt = 0; nt < 4; ++nt)
#pragma unroll
        for (int r = 0; r < 4; ++r) o[nt][qt][r] *= alpha;

#pragma unroll
      for (int kk = 0; kk < 4; ++kk) {
        short8 pf = *(const short8*)&PT[w][lrow * 136 + kk * 32 + lkg * 8];
#pragma unroll
        for (int nt = 0; nt < 4; ++nt) {
          short8 vf = *(const short8*)&VT[(nt * 16 + lrow) * 136 + kk * 32 + lkg * 8];
          o[nt][qt] = mfma16(vf, pf, o[nt][qt]);
        }
      }
    }
    nbuf ^= 1;
  }

  // ---- epilogue: write AO in staging-tiled layout for gemm64 ----
#pragma unroll
  for (int qt = 0; qt < 2; ++qt) {
    const int qq = q0 + qt * 64 + w * 16 + lrow;
    const float inv = 1.0f / l_i[qt];
#pragma unroll
    for (int nt = 0; nt < 4; ++nt) {
      floatx4 ov = o[nt][qt];
      uint32_t lo = cvt_pk_bf16(ov[0] * inv, ov[1] * inv);
      uint32_t hi = cvt_pk_bf16(ov[2] * inv, ov[3] * inv);
      int col = h * 64 + nt * 16 + lkg * 4;
      *(uint2*)&aout[tiled_off(qq, col)] = uint2{lo, hi};
    }
  }
}

// ---------------------------------------------------------------------------
extern "C" void kernel_launch(void* const* d_in, const int* in_sizes, int n_in,
                              void* d_out, int out_size, void* d_ws, size_t ws_size,
                              hipStream_t stream) {
  const float* x = (const float*)d_in[0];
  const float* wq = (const float*)d_in[1];
  const float* wk = (const float*)d_in[2];
  const float* wv = (const float*)d_in[3];
  const float* wo = (const float*)d_in[4];

  char* ws = (char*)d_ws;
  unsigned short* Xb = (unsigned short*)(ws);                 // 8 MB (tiled)
  unsigned short* Wqkv = (unsigned short*)(ws + (8u << 20));  // 6 MB (tiled)
  unsigned short* Wob = (unsigned short*)(ws + (14u << 20));  // 2 MB (tiled)
  unsigned short* QKV = (unsigned short*)(ws + (16u << 20));  // 24 MB
  unsigned short* AO = (unsigned short*)(ws + (40u << 20));   // 8 MB (tiled)

  convert_pack<<<4096, 256, 0, stream>>>(x, wq, wk, wv, wo, Xb, Wqkv, Wob);
  gemm_bt<unsigned short><<<dim3(32, 24), 256, 0, stream>>>(Xb, Wqkv, QKV, 3072, 1024);
  attn_kernel<<<512, 256, 0, stream>>>(QKV, AO);
  gemm64<<<dim3(64, 8), 256, 0, stream>>>(AO, Wob, (float*)d_out, 1024, 1024);
}